// Round 12
// baseline (227.487 us; speedup 1.0000x reference)
//
#include <hip/hip_runtime.h>
#include <math.h>

#define NNODES 50000
#define MPAD   50048            // 782 * 64
#define NFEAT  128
#define NEDGE  800000
#define ETOT   (NEDGE + NNODES) // 850000 edges incl. self-loops
#define H1     4
#define O1     256              // heads1 * hid1
#define C2     128
#define C3     10
#define NGRAPH 512

#define NBKT   196              // coarse buckets: dst >> 8
#define NBLK1  831              // 831*1024 >= ETOT
#define EPB    1024             // edges per hist/partition block
#define SCM    (NBKT * NBLK1)   // 162876 offset-table entries
#define SCB    637              // ceil(SCM/256)

typedef __attribute__((ext_vector_type(8))) short short8;
typedef __attribute__((ext_vector_type(4))) float f32x4;
typedef __attribute__((ext_vector_type(2))) float f32x2;

__device__ __forceinline__ unsigned short f2b(float f) {
  unsigned int u = __float_as_uint(f);
  u += 0x7fffu + ((u >> 16) & 1u);
  return (unsigned short)(u >> 16);
}
__device__ __forceinline__ float b2f(unsigned short u) {
  return __uint_as_float(((unsigned int)u) << 16);
}
__device__ __forceinline__ float readlane_f(float v, int l) {
  return __uint_as_float((unsigned)__builtin_amdgcn_readlane(__float_as_uint(v), l));
}

// ---------------- layer-1 prep (MUST run before k_front: cvt reads was/wad) --

__global__ void k_prep(const float* __restrict__ W1, const float* __restrict__ as1,
                       const float* __restrict__ ad1,
                       float* __restrict__ was, float* __restrict__ wad) {
  int tid = threadIdx.x;          // 512 = 4 heads x 128 k
  int h = tid >> 7, k = tid & 127;
  float s = 0.f, d = 0.f;
  for (int j = 0; j < 64; ++j) {
    float w = W1[(size_t)k * 256 + h * 64 + j];
    s += w * as1[h * 64 + j];
    d += w * ad1[h * 64 + j];
  }
  was[h * 128 + k] = s;
  wad[h * 128 + k] = d;
}

// ---------------- fused front kernel ----------------
// roles by blockIdx: [0,831) coarse histogram | [831,13331) cvt+logits |
// [13331,13459) packW1 | [13459,13587) packW2 | [13587,13595) packW3
#define NB_CVT 12500

__global__ __launch_bounds__(256) void k_front(
    const int* __restrict__ src_e, const int* __restrict__ dst_e,
    int* __restrict__ hists,
    const float* __restrict__ X, unsigned short* __restrict__ Xb,
    const float* __restrict__ W1,
    const float* __restrict__ was, const float* __restrict__ wad,
    float* __restrict__ als, float* __restrict__ ald,
    unsigned short* __restrict__ W1p,
    const float* __restrict__ W2, unsigned short* __restrict__ W2p,
    const float* __restrict__ W3, unsigned short* __restrict__ W3p) {
  const int b = blockIdx.x;
  const int tid = threadIdx.x;
  if (b < NBLK1) {                           // ---- coarse histogram (LDS only)
    __shared__ int h[NBKT];
    if (tid < NBKT) h[tid] = 0;
    __syncthreads();
    const int base = b * EPB;
#pragma unroll
    for (int r = 0; r < 4; ++r) {
      int e = base + r * 256 + tid;
      if (e < ETOT) {
        int d = (e < NEDGE) ? dst_e[e] : (e - NEDGE);
        atomicAdd(&h[d >> 8], 1);
      }
    }
    __syncthreads();
    if (tid < NBKT) hists[tid * NBLK1 + b] = h[tid];
  } else if (b < NBLK1 + NB_CVT) {           // ---- cvt X->bf16 + layer-1 logits
    const int n = (b - NBLK1) * 4 + (tid >> 6);
    const int lane = tid & 63;
    const int k0 = lane * 2;
    float2 xv = *(const float2*)(X + (size_t)n * 128 + k0);
    ushort2 o; o.x = f2b(xv.x); o.y = f2b(xv.y);
    *(ushort2*)(Xb + (size_t)n * 128 + k0) = o;
    float s[4], d[4];
#pragma unroll
    for (int h = 0; h < 4; ++h) {
      float2 wsv = *(const float2*)(was + h * 128 + k0);
      float2 wdv = *(const float2*)(wad + h * 128 + k0);
      s[h] = xv.x * wsv.x + xv.y * wsv.y;
      d[h] = xv.x * wdv.x + xv.y * wdv.y;
    }
#pragma unroll
    for (int m = 1; m < 64; m <<= 1)
#pragma unroll
      for (int h = 0; h < 4; ++h) { s[h] += __shfl_xor(s[h], m); d[h] += __shfl_xor(d[h], m); }
    if (lane == 0) {
#pragma unroll
      for (int h = 0; h < 4; ++h) {
        als[(size_t)n * 4 + h] = s[h];
        ald[(size_t)n * 4 + h] = d[h];
      }
    }
  } else if (b < NBLK1 + NB_CVT + 128) {     // ---- pack W1 per head
    int idx = (b - NBLK1 - NB_CVT) * 256 + tid;   // 4*8192
    int h = idx >> 13, r = idx & 8191;
    int j = r & 7, lane = (r >> 3) & 63, t = r >> 9;
    int ks = t & 3, nt = t >> 2;
    int k = ks * 32 + (lane >> 4) * 8 + j;
    int n = nt * 16 + (lane & 15);
    W1p[idx] = f2b(W1[(size_t)k * 256 + h * 64 + n]);
  } else if (b < NBLK1 + NB_CVT + 256) {     // ---- pack W2 (K=256,N=128)
    int idx = (b - NBLK1 - NB_CVT - 128) * 256 + tid;  // 32768
    int j = idx & 7, lane = (idx >> 3) & 63, t = idx >> 9;
    int ks = t % 8, nt = t / 8;
    int k = ks * 32 + (lane >> 4) * 8 + j;
    int n = nt * 16 + (lane & 15);
    W2p[idx] = f2b(W2[(size_t)k * C2 + n]);
  } else {                                    // ---- pack W3 (K=128,N=16,real 10)
    int idx = (b - NBLK1 - NB_CVT - 256) * 256 + tid;  // 2048
    int j = idx & 7, lane = (idx >> 3) & 63, t = idx >> 9;
    int ks = t & 3, nt = t >> 2;
    int k = ks * 32 + (lane >> 4) * 8 + j;
    int n = nt * 16 + (lane & 15);
    W3p[idx] = f2b((n < C3) ? W3[(size_t)k * C3 + n] : 0.f);
  }
}

// ---------------- offset-table scan (exclusive, over SCM ints) ----------------

__global__ __launch_bounds__(256) void k_scanA2(const int* __restrict__ a,
                                                int* __restrict__ bsum) {
  int idx = blockIdx.x * 256 + threadIdx.x;
  int v = (idx < SCM) ? a[idx] : 0;
#pragma unroll
  for (int m = 1; m < 64; m <<= 1) v += __shfl_xor(v, m);
  __shared__ int ws[4];
  int lane = threadIdx.x & 63, wid = threadIdx.x >> 6;
  if (lane == 0) ws[wid] = v;
  __syncthreads();
  if (threadIdx.x == 0) bsum[blockIdx.x] = ws[0] + ws[1] + ws[2] + ws[3];
}

__global__ __launch_bounds__(256) void k_scanMid(int* __restrict__ bsum) {
  __shared__ int ws[4];
  __shared__ int carry_s;
  const int tid = threadIdx.x, lane = tid & 63, wid = tid >> 6;
  if (tid == 0) carry_s = 0;
  __syncthreads();
  for (int base = 0; base < SCB; base += 256) {
    int j = base + tid;
    int v = (j < SCB) ? bsum[j] : 0;
    int s = v;
#pragma unroll
    for (int m = 1; m < 64; m <<= 1) {
      int t = __shfl_up(s, m);
      if (lane >= m) s += t;
    }
    if (lane == 63) ws[wid] = s;
    __syncthreads();
    int woff = 0;
#pragma unroll
    for (int k = 0; k < 4; ++k)
      if (k < wid) woff += ws[k];
    int c = carry_s;
    int tot = ws[0] + ws[1] + ws[2] + ws[3];
    if (j < SCB) bsum[j] = c + woff + s - v;   // exclusive
    __syncthreads();
    if (tid == 0) carry_s = c + tot;
    __syncthreads();
  }
}

__global__ __launch_bounds__(256) void k_scanB2(int* __restrict__ a,
                                                const int* __restrict__ bsum,
                                                int* __restrict__ cb) {
  const int b = blockIdx.x, tid = threadIdx.x;
  const int lane = tid & 63, wid = tid >> 6;
  __shared__ int ws[4];
  int idx = b * 256 + tid;
  int v = (idx < SCM) ? a[idx] : 0;
  int s = v;
#pragma unroll
  for (int m = 1; m < 64; m <<= 1) {
    int t = __shfl_up(s, m);
    if (lane >= m) s += t;
  }
  if (lane == 63) ws[wid] = s;
  __syncthreads();
  int woff = 0;
#pragma unroll
  for (int k = 0; k < 4; ++k)
    if (k < wid) woff += ws[k];
  int excl = bsum[b] + woff + s - v;
  if (idx < SCM) {
    a[idx] = excl;
    if (idx % NBLK1 == 0) cb[idx / NBLK1] = excl;   // coarse bucket base
  }
  if (b == 0 && tid == 0) cb[NBKT] = ETOT;
}

// ---------------- partition into coarse buckets (LDS atomics only) ----------

__global__ __launch_bounds__(256) void k_part1(const int* __restrict__ src_e,
                                               const int* __restrict__ dst_e,
                                               const int* __restrict__ offs,
                                               unsigned* __restrict__ coarse) {
  __shared__ int cur[NBKT];
  const int b = blockIdx.x;
  const int tid = threadIdx.x;
  if (tid < NBKT) cur[tid] = offs[tid * NBLK1 + b];
  __syncthreads();
  const int base = b * EPB;
#pragma unroll
  for (int r = 0; r < 4; ++r) {
    int e = base + r * 256 + tid;
    if (e < ETOT) {
      int d, s;
      if (e < NEDGE) { d = dst_e[e]; s = src_e[e]; }
      else           { d = e - NEDGE; s = e - NEDGE; }
      int pos = atomicAdd(&cur[d >> 8], 1);
      coarse[pos] = ((unsigned)d << 16) | (unsigned)s;
    }
  }
}

// ---------------- per-bucket fine binning -> rowptr + srcs -------------------

__global__ __launch_bounds__(256) void k_bucket(const unsigned* __restrict__ coarse,
                                                const int* __restrict__ cb,
                                                int* __restrict__ rowptr,
                                                int* __restrict__ srcs) {
  const int b = blockIdx.x;                  // 196 buckets
  const int tid = threadIdx.x;
  const int lane = tid & 63, wid = tid >> 6;
  const int lo = cb[b], hi = cb[b + 1];
  __shared__ int h[256];
  __shared__ int cur[256];
  __shared__ int ws[4];
  h[tid] = 0;
  __syncthreads();
  for (int i = lo + tid; i < hi; i += 256)
    atomicAdd(&h[(coarse[i] >> 16) & 255], 1);
  __syncthreads();
  int v = h[tid];
  int s = v;
#pragma unroll
  for (int m = 1; m < 64; m <<= 1) {
    int t = __shfl_up(s, m);
    if (lane >= m) s += t;
  }
  if (lane == 63) ws[wid] = s;
  __syncthreads();
  int woff = 0;
#pragma unroll
  for (int k = 0; k < 4; ++k)
    if (k < wid) woff += ws[k];
  int ex = woff + s - v;                     // exclusive fine scan
  cur[tid] = lo + ex;
  int d = b * 256 + tid;
  if (d < NNODES) rowptr[d] = lo + ex;
  if (b == NBKT - 1 && tid == 0) rowptr[NNODES] = ETOT;
  __syncthreads();
  for (int i = lo + tid; i < hi; i += 256) {
    unsigned c = coarse[i];
    int pos = atomicAdd(&cur[(c >> 16) & 255], 1);
    srcs[pos] = (int)(c & 0xffffu);
  }
}

// ---------------- FUSED layer 1: aggregation + per-head GEMM -----------------
// Phase 1 (per wave = 1 node): 16-edge chunks, hoisted gathers, pk_fma over
// 4 heads; P-row normalized -> LDS (bf16).  Phase 2 (per block = 8 nodes):
// 16 (head, ntile) MFMA units over A=[16x128] (rows 0..7 valid) @ W1_h
// -> act1 with bias + leaky_relu.  P never touches global memory.

__global__ __launch_bounds__(512) void k_aggP(const int* __restrict__ rowptr,
                                              const int* __restrict__ srcs,
                                              const unsigned short* __restrict__ Xb,
                                              const float* __restrict__ als,
                                              const float* __restrict__ ald,
                                              const unsigned short* __restrict__ W1p,
                                              const float* __restrict__ b1,
                                              unsigned short* __restrict__ act1) {
  __shared__ float exs[8][16][4];            // [wave][edge][head]
  __shared__ unsigned short Pl[8][4][128];   // 8 KB: P rows for the block
  const int wv = threadIdx.x >> 6;
  const int n = blockIdx.x * 8 + wv;
  const int lane = threadIdx.x & 63;
  const int r0 = rowptr[n], r1 = rowptr[n + 1];
  const int e_lane = lane & 15, hh = lane >> 4;
  const float aldv = ald[(size_t)n * 4 + hh];
  const int ch0 = lane * 2;
  f32x2 ah0 = {0.f, 0.f}, ah1 = {0.f, 0.f}, ah2 = {0.f, 0.f}, ah3 = {0.f, 0.f};
  float den = 0.f;
  for (int i0 = r0; i0 < r1; i0 += 16) {
    const int take = r1 - i0;
    int sidx = srcs[min(i0 + e_lane, r1 - 1)];
    float ev = als[(size_t)sidx * 4 + hh] + aldv;
    ev = (ev > 0.f) ? ev : 0.2f * ev;
    float exv = (e_lane < take) ? __expf(ev) : 0.f;
    den += exv;
    exs[wv][e_lane][hh] = exv;
    unsigned hv[16];
#pragma unroll
    for (int m = 0; m < 16; ++m) {
      int s = __builtin_amdgcn_readlane(sidx, m);
      hv[m] = *(const unsigned*)(Xb + (size_t)s * 128 + ch0);
    }
#pragma unroll
    for (int m = 0; m < 16; ++m) {
      f32x2 e01 = *(const f32x2*)(&exs[wv][m][0]);
      f32x2 e23 = *(const f32x2*)(&exs[wv][m][2]);
      f32x2 x2;
      x2.x = __uint_as_float(hv[m] << 16);
      x2.y = __uint_as_float(hv[m] & 0xffff0000u);
      asm("v_pk_fma_f32 %0, %1, %2, %0 op_sel:[0,0,0] op_sel_hi:[1,0,1]"
          : "+v"(ah0) : "v"(x2), "v"(e01));
      asm("v_pk_fma_f32 %0, %1, %2, %0 op_sel:[0,1,0] op_sel_hi:[1,1,1]"
          : "+v"(ah1) : "v"(x2), "v"(e01));
      asm("v_pk_fma_f32 %0, %1, %2, %0 op_sel:[0,0,0] op_sel_hi:[1,0,1]"
          : "+v"(ah2) : "v"(x2), "v"(e23));
      asm("v_pk_fma_f32 %0, %1, %2, %0 op_sel:[0,1,0] op_sel_hi:[1,1,1]"
          : "+v"(ah3) : "v"(x2), "v"(e23));
    }
  }
#pragma unroll
  for (int m = 1; m < 16; m <<= 1) den += __shfl_xor(den, m);
  float acc[4][2] = {{ah0.x, ah0.y}, {ah1.x, ah1.y}, {ah2.x, ah2.y}, {ah3.x, ah3.y}};
#pragma unroll
  for (int h = 0; h < 4; ++h) {
    float rd = 1.f / (readlane_f(den, h * 16) + 1e-16f);
    ushort2 o; o.x = f2b(acc[h][0] * rd); o.y = f2b(acc[h][1] * rd);
    *(ushort2*)(&Pl[wv][h][ch0]) = o;
  }
  __syncthreads();

  // ---- phase 2: 16 (h, nt) units over 8 waves (2 each)
  const int row = lane & 15;                 // A row (node within block)
  const int k0 = (lane >> 4) * 8;
  const int col = lane & 15;
  const int rb = (lane >> 4) * 4;
#pragma unroll
  for (int u = 0; u < 2; ++u) {
    const int unit = wv + 8 * u;             // 0..15
    const int h = unit >> 2, nt = unit & 3;
    f32x4 acc2 = {};
#pragma unroll
    for (int ks = 0; ks < 4; ++ks) {
      short8 a{};
      if (row < 8) a = *(const short8*)(&Pl[row][h][ks * 32 + k0]);
      short8 b = *((const short8*)(W1p + (size_t)h * 8192) + nt * 256 + ks * 64 + lane);
      acc2 = __builtin_amdgcn_mfma_f32_16x16x32_bf16(a, b, acc2, 0, 0, 0);
    }
    const int ch = h * 64 + nt * 16 + col;
    const float bb = b1[ch];
#pragma unroll
    for (int j = 0; j < 4; ++j) {
      int r = rb + j;
      if (r < 8) {
        float v = acc2[j] + bb;
        v = (v > 0.f) ? v : 0.01f * v;
        act1[(size_t)(blockIdx.x * 8 + r) * 256 + ch] = f2b(v);
      }
    }
  }
}

// ---------------- MFMA GEMM + fused attention-logit epilogue (layer 2) ------

template<int K, int N, int HEADS, int CREAL>
__global__ __launch_bounds__(256) void k_mm(const unsigned short* __restrict__ Xb,
                                            const unsigned short* __restrict__ Wp,
                                            unsigned short* __restrict__ Hout,
                                            const float* __restrict__ a_src,
                                            const float* __restrict__ a_dst,
                                            float* __restrict__ als,
                                            float* __restrict__ ald) {
  constexpr int KS = K / 32, NT = N / 16;
  constexpr int NTH = (NT + HEADS - 1) / HEADS;
  const int w = threadIdx.x >> 6, lane = threadIdx.x & 63;
  const int arow = blockIdx.x * 64 + w * 16 + (lane & 15);
  const int k0 = (lane >> 4) * 8;
  f32x4 acc[NT] = {};
  for (int ks = 0; ks < KS; ++ks) {
    short8 a = *(const short8*)(Xb + (size_t)arow * K + ks * 32 + k0);
    const short8* bp = (const short8*)Wp + (size_t)ks * 64 + lane;
#pragma unroll
    for (int nt = 0; nt < NT; ++nt) {
      short8 b = bp[(size_t)nt * KS * 64];
      acc[nt] = __builtin_amdgcn_mfma_f32_16x16x32_bf16(a, b, acc[nt], 0, 0, 0);
    }
  }
  const int col = lane & 15;
  const int rbase = blockIdx.x * 64 + w * 16 + (lane >> 4) * 4;
#pragma unroll
  for (int nt = 0; nt < NT; ++nt)
#pragma unroll
    for (int j = 0; j < 4; ++j)
      Hout[(size_t)(rbase + j) * N + nt * 16 + col] = f2b(acc[nt][j]);

  float av[NT], dv[NT];
#pragma unroll
  for (int nt = 0; nt < NT; ++nt) {
    int ch = nt * 16 + col;
    av[nt] = (ch < CREAL) ? a_src[ch] : 0.f;
    dv[nt] = (ch < CREAL) ? a_dst[ch] : 0.f;
  }
  float sa[HEADS][4], da[HEADS][4];
#pragma unroll
  for (int h = 0; h < HEADS; ++h)
#pragma unroll
    for (int j = 0; j < 4; ++j) { sa[h][j] = 0.f; da[h][j] = 0.f; }
#pragma unroll
  for (int nt = 0; nt < NT; ++nt) {
    int h = nt / NTH;
#pragma unroll
    for (int j = 0; j < 4; ++j) {
      sa[h][j] += acc[nt][j] * av[nt];
      da[h][j] += acc[nt][j] * dv[nt];
    }
  }
#pragma unroll
  for (int mask = 1; mask < 16; mask <<= 1)
#pragma unroll
    for (int h = 0; h < HEADS; ++h)
#pragma unroll
      for (int j = 0; j < 4; ++j) {
        sa[h][j] += __shfl_xor(sa[h][j], mask);
        da[h][j] += __shfl_xor(da[h][j], mask);
      }
  if (col == 0) {
#pragma unroll
    for (int j = 0; j < 4; ++j)
#pragma unroll
      for (int h = 0; h < HEADS; ++h) {
        als[(size_t)(rbase + j) * HEADS + h] = sa[h][j];
        ald[(size_t)(rbase + j) * HEADS + h] = da[h][j];
      }
  }
}

// ---------------- FUSED layer 2 agg + layer-3 GEMM + att3 logits -------------
// Phase 1: aggregation over Hb (edge-paired pk_fma), bias + lrelu -> LDS.
// Phase 2 (wave 0): A=[16x128] (8 valid rows) @ W3p -> H3b + als3/ald3.
// Xc never touches global memory.

__global__ __launch_bounds__(512) void k_agg2(const int* __restrict__ rowptr,
                                              const int* __restrict__ srcs,
                                              const unsigned short* __restrict__ Hm,
                                              const float* __restrict__ als,
                                              const float* __restrict__ ald,
                                              const float* __restrict__ bias,
                                              const unsigned short* __restrict__ W3p,
                                              const float* __restrict__ as3,
                                              const float* __restrict__ ad3,
                                              unsigned short* __restrict__ H3b,
                                              float* __restrict__ als3,
                                              float* __restrict__ ald3) {
  __shared__ float exs2[8][16];
  __shared__ unsigned short Xl[8][128];      // 2 KB: activated rows
  const int wv = threadIdx.x >> 6;
  const int n = blockIdx.x * 8 + wv;
  const int lane = threadIdx.x & 63;
  const int r0 = rowptr[n], r1 = rowptr[n + 1];
  const int e_lane = lane & 15;
  const int ch0 = lane * 2;
  const float aldm = ald[n];
  f32x2 accP0 = {0.f, 0.f}, accP1 = {0.f, 0.f};
  float den = 0.f;
  for (int i0 = r0; i0 < r1; i0 += 16) {
    const int take = r1 - i0;
    int sidx = srcs[min(i0 + e_lane, r1 - 1)];
    float ev = als[sidx] + aldm;
    ev = (ev > 0.f) ? ev : 0.2f * ev;
    float exv = (lane < 16 && e_lane < take) ? __expf(ev) : 0.f;
    den += exv;
    if (lane < 16) exs2[wv][lane] = exv;
    unsigned hv[16];
#pragma unroll
    for (int m = 0; m < 16; ++m) {
      int s = __builtin_amdgcn_readlane(sidx, m);
      hv[m] = *(const unsigned*)(Hm + (size_t)s * C2 + ch0);
    }
#pragma unroll
    for (int m = 0; m < 16; m += 2) {
      f32x2 ep = *(const f32x2*)(&exs2[wv][m]);
      f32x2 xa, xb;
      xa.x = __uint_as_float(hv[m] << 16);
      xa.y = __uint_as_float(hv[m + 1] << 16);
      xb.x = __uint_as_float(hv[m] & 0xffff0000u);
      xb.y = __uint_as_float(hv[m + 1] & 0xffff0000u);
      asm("v_pk_fma_f32 %0, %1, %2, %0" : "+v"(accP0) : "v"(ep), "v"(xa));
      asm("v_pk_fma_f32 %0, %1, %2, %0" : "+v"(accP1) : "v"(ep), "v"(xb));
    }
  }
#pragma unroll
  for (int mask = 1; mask < 64; mask <<= 1) den += __shfl_xor(den, mask);
  float rden = 1.f / (den + 1e-16f);
  float v0 = (accP0.x + accP0.y) * rden + bias[ch0];
  float v1 = (accP1.x + accP1.y) * rden + bias[ch0 + 1];
  v0 = (v0 > 0.f) ? v0 : 0.01f * v0;
  v1 = (v1 > 0.f) ? v1 : 0.01f * v1;
  ushort2 o; o.x = f2b(v0); o.y = f2b(v1);
  *(ushort2*)(&Xl[wv][ch0]) = o;
  __syncthreads();

  // ---- phase 2 (wave 0): 128->16 GEMM + att3 logits for the 8 nodes
  if (wv == 0) {
    const int row = lane & 15;
    const int k0 = (lane >> 4) * 8;
    const int col = lane & 15;
    f32x4 acc2 = {};
#pragma unroll
    for (int ks = 0; ks < 4; ++ks) {
      short8 a{};
      if (row < 8) a = *(const short8*)(&Xl[row][ks * 32 + k0]);
      short8 b = *((const short8*)W3p + ks * 64 + lane);
      acc2 = __builtin_amdgcn_mfma_f32_16x16x32_bf16(a, b, acc2, 0, 0, 0);
    }
    const float av = (col < C3) ? as3[col] : 0.f;
    const float dv = (col < C3) ? ad3[col] : 0.f;
    const int rb = (lane >> 4) * 4;
#pragma unroll
    for (int j = 0; j < 4; ++j) {
      float hv = acc2[j];
      float sa = hv * av, da = hv * dv;
#pragma unroll
      for (int mask = 1; mask < 16; mask <<= 1) {
        sa += __shfl_xor(sa, mask);
        da += __shfl_xor(da, mask);
      }
      int r = rb + j;
      if (r < 8) {
        int node = blockIdx.x * 8 + r;
        H3b[(size_t)node * 16 + col] = f2b(hv);
        if (col == 0) { als3[node] = sa; ald3[node] = da; }
      }
    }
  }
}

// ---------------- layer-3 aggregation + fused pool: 4 nodes/wave -------------

__global__ __launch_bounds__(512) void k_agg3(const int* __restrict__ rowptr,
                                              const int* __restrict__ srcs,
                                              const unsigned short* __restrict__ Hm,
                                              const float* __restrict__ als,
                                              const float* __restrict__ ald,
                                              const float* __restrict__ bias,
                                              float* __restrict__ pooled,
                                              const int* __restrict__ batch) {
  __shared__ int   sid_s[8][4][16];
  __shared__ float exv_s[8][4][16];
  const int wv = threadIdx.x >> 6;
  const int lane = threadIdx.x & 63;
  const int g = lane >> 4, el = lane & 15;
  const int n = blockIdx.x * 32 + wv * 4 + g;
  const bool valid = n < NNODES;
  int r0 = 0, r1 = 0;
  float aldm = 0.f;
  if (valid) { r0 = rowptr[n]; r1 = rowptr[n + 1]; aldm = ald[n]; }
  float acc = 0.f, den = 0.f;
  for (int i0 = r0; i0 < r1; i0 += 16) {
    const int take = r1 - i0;
    int sidx = srcs[min(i0 + el, r1 - 1)];
    float ev = als[sidx] + aldm;
    ev = (ev > 0.f) ? ev : 0.2f * ev;
    float exv = (el < take) ? __expf(ev) : 0.f;
    den += exv;
    sid_s[wv][g][el] = sidx;
    exv_s[wv][g][el] = exv;
#pragma unroll
    for (int m = 0; m < 16; ++m) {
      int s = sid_s[wv][g][m];
      float ex = exv_s[wv][g][m];
      acc += ex * b2f(Hm[(size_t)s * 16 + el]);
    }
  }
#pragma unroll
  for (int mask = 1; mask < 16; mask <<= 1) den += __shfl_xor(den, mask);
  if (valid && el < C3) {
    float val = acc / (den + 1e-16f) + bias[el];
    atomicAdd(&pooled[(size_t)batch[n] * C3 + el], val);
  }
}

// ---------------- log_softmax ----------------

__global__ void k_lsm(const float* __restrict__ pooled, float* __restrict__ dout) {
  int g = blockIdx.x * 256 + threadIdx.x;
  if (g >= NGRAPH) return;
  float v[C3];
  float mx = -1e30f;
#pragma unroll
  for (int c = 0; c < C3; ++c) { v[c] = pooled[g * C3 + c]; mx = fmaxf(mx, v[c]); }
  float ssum = 0.f;
#pragma unroll
  for (int c = 0; c < C3; ++c) ssum += __expf(v[c] - mx);
  float lse = mx + __logf(ssum);
#pragma unroll
  for (int c = 0; c < C3; ++c) {
    dout[g * C3 + c] = v[c] - lse;
    dout[NGRAPH * C3 + g * C3 + c] = v[c];
  }
}

// ---------------- launcher ----------------

extern "C" void kernel_launch(void* const* d_in, const int* in_sizes, int n_in,
                              void* d_out, int out_size, void* d_ws, size_t ws_size,
                              hipStream_t stream) {
  (void)in_sizes; (void)n_in; (void)out_size; (void)ws_size;
  const float* x     = (const float*)d_in[0];
  const int*   eix   = (const int*)d_in[1];
  const int*   batch = (const int*)d_in[3];
  const float* W1 = (const float*)d_in[4];
  const float* as1 = (const float*)d_in[5];
  const float* ad1 = (const float*)d_in[6];
  const float* b1 = (const float*)d_in[7];
  const float* W2 = (const float*)d_in[8];
  const float* as2 = (const float*)d_in[9];
  const float* ad2 = (const float*)d_in[10];
  const float* b2 = (const float*)d_in[11];
  const float* W3 = (const float*)d_in[12];
  const float* as3 = (const float*)d_in[13];
  const float* ad3 = (const float*)d_in[14];
  const float* b3 = (const float*)d_in[15];
  const int* src_e = eix;
  const int* dst_e = eix + NEDGE;

  char* ws = (char*)d_ws;
  size_t off = 0;
  auto carve = [&](size_t bytes) -> char* {
    char* p = ws + off;
    off += (bytes + 511) & ~(size_t)511;
    return p;
  };
  int* hists  = (int*)carve((size_t)SCM * 4);
  int* bsum   = (int*)carve((size_t)SCB * 4);
  int* cb     = (int*)carve((size_t)(NBKT + 1) * 4);
  unsigned* coarse = (unsigned*)carve((size_t)ETOT * 4);
  int* rowptr = (int*)carve((size_t)(NNODES + 1) * 4);
  int* srcs   = (int*)carve((size_t)ETOT * 4);
  float* als  = (float*)carve((size_t)MPAD * H1 * 4);
  float* ald  = (float*)carve((size_t)MPAD * H1 * 4);
  float* als3 = (float*)carve((size_t)MPAD * 4);
  float* ald3 = (float*)carve((size_t)MPAD * 4);
  float* was  = (float*)carve((size_t)512 * 4);
  float* wad  = (float*)carve((size_t)512 * 4);
  unsigned short* Xb   = (unsigned short*)carve((size_t)MPAD * 128 * 2);
  unsigned short* act1 = (unsigned short*)carve((size_t)MPAD * 256 * 2);
  unsigned short* Hb   = (unsigned short*)carve((size_t)MPAD * 128 * 2);
  unsigned short* H3b  = (unsigned short*)carve((size_t)MPAD * 16 * 2);
  float* pooled = (float*)carve((size_t)NGRAPH * C3 * 4);
  unsigned short* W1p = (unsigned short*)carve((size_t)4 * 8192 * 2);
  unsigned short* W2p = (unsigned short*)carve((size_t)O1 * C2 * 2);
  unsigned short* W3p = (unsigned short*)carve((size_t)C2 * 16 * 2);

  hipMemsetAsync(pooled, 0, (size_t)NGRAPH * C3 * 4, stream);

  // prep FIRST (k_front's cvt blocks read was/wad)
  k_prep<<<1, 512, 0, stream>>>(W1, as1, ad1, was, wad);
  // fused: coarse histogram + cvt/logits + weight packs
  k_front<<<NBLK1 + NB_CVT + 264, 256, 0, stream>>>(
      src_e, dst_e, hists, x, Xb, W1, was, wad, als, ald, W1p, W2, W2p, W3, W3p);
  // exclusive scan of the (bin, block) offset table; emits coarse bases cb
  k_scanA2<<<SCB, 256, 0, stream>>>(hists, bsum);
  k_scanMid<<<1, 256, 0, stream>>>(bsum);
  k_scanB2<<<SCB, 256, 0, stream>>>(hists, bsum, cb);
  // partition edges into coarse buckets, then fine-bin -> rowptr + srcs
  k_part1<<<NBLK1, 256, 0, stream>>>(src_e, dst_e, hists, coarse);
  k_bucket<<<NBKT, 256, 0, stream>>>(coarse, cb, rowptr, srcs);

  const int GB = MPAD / 64;        // 782 gemm blocks
  const int NB8 = NNODES / 8;      // 6250 fused-agg blocks (8 nodes each)
  const int NB32 = (NNODES + 31) / 32;   // 1563 agg3 blocks (4 nodes/wave)

  // layer 1: fused aggregate-in-128-basis + per-head GEMM (P stays in LDS)
  k_aggP<<<NB8, 512, 0, stream>>>(rowptr, srcs, Xb, als, ald, W1p, b1, act1);

  // layer 2: GEMM (256->128) + logits, then fused agg + layer-3 GEMM + logits
  k_mm<O1, C2, 1, C2><<<GB, 256, 0, stream>>>(act1, W2p, Hb, as2, ad2, als, ald);
  k_agg2<<<NB8, 512, 0, stream>>>(rowptr, srcs, Hb, als, ald, b2,
                                  W3p, as3, ad3, H3b, als3, ald3);

  // layer 3: aggregate + fused pool
  k_agg3<<<NB32, 512, 0, stream>>>(rowptr, srcs, H3b, als3, ald3, b3, pooled, batch);

  // log_softmax; output = [log_softmax | pooled]
  k_lsm<<<(NGRAPH + 255) / 256, 256, 0, stream>>>(pooled, (float*)d_out);
}

// Round 13
// 222.033 us; speedup vs baseline: 1.0246x; 1.0246x over previous
//
#include <hip/hip_runtime.h>
#include <math.h>

#define NNODES 50000
#define MPAD   50048            // 782 * 64
#define NFEAT  128
#define NEDGE  800000
#define ETOT   (NEDGE + NNODES) // 850000 edges incl. self-loops
#define H1     4
#define O1     256              // heads1 * hid1
#define C2     128
#define C3     10
#define NGRAPH 512

#define NBKT   196              // coarse buckets: dst >> 8
#define NBLK1  831              // 831*1024 >= ETOT
#define EPB    1024             // edges per hist/partition block
#define SCM    (NBKT * NBLK1)   // 162876 offset-table entries
#define SCB    637              // ceil(SCM/256)

typedef __attribute__((ext_vector_type(8))) short short8;
typedef __attribute__((ext_vector_type(4))) float f32x4;
typedef __attribute__((ext_vector_type(2))) float f32x2;

__device__ __forceinline__ unsigned short f2b(float f) {
  unsigned int u = __float_as_uint(f);
  u += 0x7fffu + ((u >> 16) & 1u);
  return (unsigned short)(u >> 16);
}
__device__ __forceinline__ float b2f(unsigned short u) {
  return __uint_as_float(((unsigned int)u) << 16);
}
__device__ __forceinline__ float readlane_f(float v, int l) {
  return __uint_as_float((unsigned)__builtin_amdgcn_readlane(__float_as_uint(v), l));
}

// ---------------- layer-1 prep (MUST run before k_front: cvt reads was/wad) --

__global__ void k_prep(const float* __restrict__ W1, const float* __restrict__ as1,
                       const float* __restrict__ ad1,
                       float* __restrict__ was, float* __restrict__ wad) {
  int tid = threadIdx.x;          // 512 = 4 heads x 128 k
  int h = tid >> 7, k = tid & 127;
  float s = 0.f, d = 0.f;
  for (int j = 0; j < 64; ++j) {
    float w = W1[(size_t)k * 256 + h * 64 + j];
    s += w * as1[h * 64 + j];
    d += w * ad1[h * 64 + j];
  }
  was[h * 128 + k] = s;
  wad[h * 128 + k] = d;
}

// ---------------- fused front kernel ----------------
#define NB_CVT 12500

__global__ __launch_bounds__(256) void k_front(
    const int* __restrict__ src_e, const int* __restrict__ dst_e,
    int* __restrict__ hists,
    const float* __restrict__ X, unsigned short* __restrict__ Xb,
    const float* __restrict__ W1,
    const float* __restrict__ was, const float* __restrict__ wad,
    float* __restrict__ als, float* __restrict__ ald,
    unsigned short* __restrict__ W1p,
    const float* __restrict__ W2, unsigned short* __restrict__ W2p,
    const float* __restrict__ W3, unsigned short* __restrict__ W3p) {
  const int b = blockIdx.x;
  const int tid = threadIdx.x;
  if (b < NBLK1) {                           // ---- coarse histogram (LDS only)
    __shared__ int h[NBKT];
    if (tid < NBKT) h[tid] = 0;
    __syncthreads();
    const int base = b * EPB;
#pragma unroll
    for (int r = 0; r < 4; ++r) {
      int e = base + r * 256 + tid;
      if (e < ETOT) {
        int d = (e < NEDGE) ? dst_e[e] : (e - NEDGE);
        atomicAdd(&h[d >> 8], 1);
      }
    }
    __syncthreads();
    if (tid < NBKT) hists[tid * NBLK1 + b] = h[tid];
  } else if (b < NBLK1 + NB_CVT) {           // ---- cvt X->bf16 + layer-1 logits
    const int n = (b - NBLK1) * 4 + (tid >> 6);
    const int lane = tid & 63;
    const int k0 = lane * 2;
    float2 xv = *(const float2*)(X + (size_t)n * 128 + k0);
    ushort2 o; o.x = f2b(xv.x); o.y = f2b(xv.y);
    *(ushort2*)(Xb + (size_t)n * 128 + k0) = o;
    float s[4], d[4];
#pragma unroll
    for (int h = 0; h < 4; ++h) {
      float2 wsv = *(const float2*)(was + h * 128 + k0);
      float2 wdv = *(const float2*)(wad + h * 128 + k0);
      s[h] = xv.x * wsv.x + xv.y * wsv.y;
      d[h] = xv.x * wdv.x + xv.y * wdv.y;
    }
#pragma unroll
    for (int m = 1; m < 64; m <<= 1)
#pragma unroll
      for (int h = 0; h < 4; ++h) { s[h] += __shfl_xor(s[h], m); d[h] += __shfl_xor(d[h], m); }
    if (lane == 0) {
#pragma unroll
      for (int h = 0; h < 4; ++h) {
        als[(size_t)n * 4 + h] = s[h];
        ald[(size_t)n * 4 + h] = d[h];
      }
    }
  } else if (b < NBLK1 + NB_CVT + 128) {     // ---- pack W1 per head
    int idx = (b - NBLK1 - NB_CVT) * 256 + tid;   // 4*8192
    int h = idx >> 13, r = idx & 8191;
    int j = r & 7, lane = (r >> 3) & 63, t = r >> 9;
    int ks = t & 3, nt = t >> 2;
    int k = ks * 32 + (lane >> 4) * 8 + j;
    int n = nt * 16 + (lane & 15);
    W1p[idx] = f2b(W1[(size_t)k * 256 + h * 64 + n]);
  } else if (b < NBLK1 + NB_CVT + 256) {     // ---- pack W2 (K=256,N=128)
    int idx = (b - NBLK1 - NB_CVT - 128) * 256 + tid;  // 32768
    int j = idx & 7, lane = (idx >> 3) & 63, t = idx >> 9;
    int ks = t % 8, nt = t / 8;
    int k = ks * 32 + (lane >> 4) * 8 + j;
    int n = nt * 16 + (lane & 15);
    W2p[idx] = f2b(W2[(size_t)k * C2 + n]);
  } else {                                    // ---- pack W3 (K=128,N=16,real 10)
    int idx = (b - NBLK1 - NB_CVT - 256) * 256 + tid;  // 2048
    int j = idx & 7, lane = (idx >> 3) & 63, t = idx >> 9;
    int ks = t & 3, nt = t >> 2;
    int k = ks * 32 + (lane >> 4) * 8 + j;
    int n = nt * 16 + (lane & 15);
    W3p[idx] = f2b((n < C3) ? W3[(size_t)k * C3 + n] : 0.f);
  }
}

// ---------------- offset-table scan (exclusive, over SCM ints) ----------------

__global__ __launch_bounds__(256) void k_scanA2(const int* __restrict__ a,
                                                int* __restrict__ bsum) {
  int idx = blockIdx.x * 256 + threadIdx.x;
  int v = (idx < SCM) ? a[idx] : 0;
#pragma unroll
  for (int m = 1; m < 64; m <<= 1) v += __shfl_xor(v, m);
  __shared__ int ws[4];
  int lane = threadIdx.x & 63, wid = threadIdx.x >> 6;
  if (lane == 0) ws[wid] = v;
  __syncthreads();
  if (threadIdx.x == 0) bsum[blockIdx.x] = ws[0] + ws[1] + ws[2] + ws[3];
}

__global__ __launch_bounds__(256) void k_scanMid(int* __restrict__ bsum) {
  __shared__ int ws[4];
  __shared__ int carry_s;
  const int tid = threadIdx.x, lane = tid & 63, wid = tid >> 6;
  if (tid == 0) carry_s = 0;
  __syncthreads();
  for (int base = 0; base < SCB; base += 256) {
    int j = base + tid;
    int v = (j < SCB) ? bsum[j] : 0;
    int s = v;
#pragma unroll
    for (int m = 1; m < 64; m <<= 1) {
      int t = __shfl_up(s, m);
      if (lane >= m) s += t;
    }
    if (lane == 63) ws[wid] = s;
    __syncthreads();
    int woff = 0;
#pragma unroll
    for (int k = 0; k < 4; ++k)
      if (k < wid) woff += ws[k];
    int c = carry_s;
    int tot = ws[0] + ws[1] + ws[2] + ws[3];
    if (j < SCB) bsum[j] = c + woff + s - v;   // exclusive
    __syncthreads();
    if (tid == 0) carry_s = c + tot;
    __syncthreads();
  }
}

__global__ __launch_bounds__(256) void k_scanB2(int* __restrict__ a,
                                                const int* __restrict__ bsum,
                                                int* __restrict__ cb) {
  const int b = blockIdx.x, tid = threadIdx.x;
  const int lane = tid & 63, wid = tid >> 6;
  __shared__ int ws[4];
  int idx = b * 256 + tid;
  int v = (idx < SCM) ? a[idx] : 0;
  int s = v;
#pragma unroll
  for (int m = 1; m < 64; m <<= 1) {
    int t = __shfl_up(s, m);
    if (lane >= m) s += t;
  }
  if (lane == 63) ws[wid] = s;
  __syncthreads();
  int woff = 0;
#pragma unroll
  for (int k = 0; k < 4; ++k)
    if (k < wid) woff += ws[k];
  int excl = bsum[b] + woff + s - v;
  if (idx < SCM) {
    a[idx] = excl;
    if (idx % NBLK1 == 0) cb[idx / NBLK1] = excl;   // coarse bucket base
  }
  if (b == 0 && tid == 0) cb[NBKT] = ETOT;
}

// ---------------- partition into coarse buckets (LDS atomics only) ----------

__global__ __launch_bounds__(256) void k_part1(const int* __restrict__ src_e,
                                               const int* __restrict__ dst_e,
                                               const int* __restrict__ offs,
                                               unsigned* __restrict__ coarse) {
  __shared__ int cur[NBKT];
  const int b = blockIdx.x;
  const int tid = threadIdx.x;
  if (tid < NBKT) cur[tid] = offs[tid * NBLK1 + b];
  __syncthreads();
  const int base = b * EPB;
#pragma unroll
  for (int r = 0; r < 4; ++r) {
    int e = base + r * 256 + tid;
    if (e < ETOT) {
      int d, s;
      if (e < NEDGE) { d = dst_e[e]; s = src_e[e]; }
      else           { d = e - NEDGE; s = e - NEDGE; }
      int pos = atomicAdd(&cur[d >> 8], 1);
      coarse[pos] = ((unsigned)d << 16) | (unsigned)s;
    }
  }
}

// ---------------- per-bucket fine binning -> rowptr + srcs -------------------

__global__ __launch_bounds__(256) void k_bucket(const unsigned* __restrict__ coarse,
                                                const int* __restrict__ cb,
                                                int* __restrict__ rowptr,
                                                int* __restrict__ srcs) {
  const int b = blockIdx.x;                  // 196 buckets
  const int tid = threadIdx.x;
  const int lane = tid & 63, wid = tid >> 6;
  const int lo = cb[b], hi = cb[b + 1];
  __shared__ int h[256];
  __shared__ int cur[256];
  __shared__ int ws[4];
  h[tid] = 0;
  __syncthreads();
  for (int i = lo + tid; i < hi; i += 256)
    atomicAdd(&h[(coarse[i] >> 16) & 255], 1);
  __syncthreads();
  int v = h[tid];
  int s = v;
#pragma unroll
  for (int m = 1; m < 64; m <<= 1) {
    int t = __shfl_up(s, m);
    if (lane >= m) s += t;
  }
  if (lane == 63) ws[wid] = s;
  __syncthreads();
  int woff = 0;
#pragma unroll
  for (int k = 0; k < 4; ++k)
    if (k < wid) woff += ws[k];
  int ex = woff + s - v;                     // exclusive fine scan
  cur[tid] = lo + ex;
  int d = b * 256 + tid;
  if (d < NNODES) rowptr[d] = lo + ex;
  if (b == NBKT - 1 && tid == 0) rowptr[NNODES] = ETOT;
  __syncthreads();
  for (int i = lo + tid; i < hi; i += 256) {
    unsigned c = coarse[i];
    int pos = atomicAdd(&cur[(c >> 16) & 255], 1);
    srcs[pos] = (int)(c & 0xffffu);
  }
}

// ---------------- layer-1 pre-GEMM aggregation (128 ch, 4 heads) ----
// Split form (no barrier coupling): one wave per node, 16-edge chunks,
// hoisted gathers, pk_fma; P written to global.

__global__ __launch_bounds__(512) void k_aggP(const int* __restrict__ rowptr,
                                              const int* __restrict__ srcs,
                                              const unsigned short* __restrict__ Xb,
                                              const float* __restrict__ als,
                                              const float* __restrict__ ald,
                                              unsigned short* __restrict__ P) {
  __shared__ float exs[8][16][4];           // [wave][edge][head]
  const int wv = threadIdx.x >> 6;
  const int n = blockIdx.x * 8 + wv;
  const int lane = threadIdx.x & 63;
  const int r0 = rowptr[n], r1 = rowptr[n + 1];
  const int e_lane = lane & 15, hh = lane >> 4;
  const float aldv = ald[(size_t)n * 4 + hh];
  const int ch0 = lane * 2;
  f32x2 ah0 = {0.f, 0.f}, ah1 = {0.f, 0.f}, ah2 = {0.f, 0.f}, ah3 = {0.f, 0.f};
  float den = 0.f;
  for (int i0 = r0; i0 < r1; i0 += 16) {
    const int take = r1 - i0;
    int sidx = srcs[min(i0 + e_lane, r1 - 1)];
    float ev = als[(size_t)sidx * 4 + hh] + aldv;
    ev = (ev > 0.f) ? ev : 0.2f * ev;
    float exv = (e_lane < take) ? __expf(ev) : 0.f;
    den += exv;
    exs[wv][e_lane][hh] = exv;
    unsigned hv[16];
#pragma unroll
    for (int m = 0; m < 16; ++m) {
      int s = __builtin_amdgcn_readlane(sidx, m);
      hv[m] = *(const unsigned*)(Xb + (size_t)s * 128 + ch0);
    }
#pragma unroll
    for (int m = 0; m < 16; ++m) {
      f32x2 e01 = *(const f32x2*)(&exs[wv][m][0]);
      f32x2 e23 = *(const f32x2*)(&exs[wv][m][2]);
      f32x2 x2;
      x2.x = __uint_as_float(hv[m] << 16);
      x2.y = __uint_as_float(hv[m] & 0xffff0000u);
      asm("v_pk_fma_f32 %0, %1, %2, %0 op_sel:[0,0,0] op_sel_hi:[1,0,1]"
          : "+v"(ah0) : "v"(x2), "v"(e01));
      asm("v_pk_fma_f32 %0, %1, %2, %0 op_sel:[0,1,0] op_sel_hi:[1,1,1]"
          : "+v"(ah1) : "v"(x2), "v"(e01));
      asm("v_pk_fma_f32 %0, %1, %2, %0 op_sel:[0,0,0] op_sel_hi:[1,0,1]"
          : "+v"(ah2) : "v"(x2), "v"(e23));
      asm("v_pk_fma_f32 %0, %1, %2, %0 op_sel:[0,1,0] op_sel_hi:[1,1,1]"
          : "+v"(ah3) : "v"(x2), "v"(e23));
    }
  }
#pragma unroll
  for (int m = 1; m < 16; m <<= 1) den += __shfl_xor(den, m);
  float acc[4][2] = {{ah0.x, ah0.y}, {ah1.x, ah1.y}, {ah2.x, ah2.y}, {ah3.x, ah3.y}};
#pragma unroll
  for (int h = 0; h < 4; ++h) {
    float rd = 1.f / (readlane_f(den, h * 16) + 1e-16f);
    ushort2 o; o.x = f2b(acc[h][0] * rd); o.y = f2b(acc[h][1] * rd);
    *(ushort2*)(P + ((size_t)n * 4 + h) * 128 + ch0) = o;
  }
}

// ---------------- FUSED GEMM chain: act1 = lrelu(P@W1+b1); H2 = act1@W2 ------
// Per 64-node block (uniform work, barrier is free):
// phase A: 4 waves compute the 64x256 act tile -> 32 KB LDS, XOR-swizzled.
// phase B: standard K=256 MFMA GEMM from LDS -> Hb + layer-2 logits.
// act1 never touches global memory.

__global__ __launch_bounds__(256) void k_mmX(
    const unsigned short* __restrict__ P,
    const unsigned short* __restrict__ W1p, const float* __restrict__ b1,
    const unsigned short* __restrict__ W2p,
    const float* __restrict__ as2, const float* __restrict__ ad2,
    unsigned short* __restrict__ Hout,
    float* __restrict__ als, float* __restrict__ ald) {
  __shared__ unsigned short actl[64 * 256];   // 32 KB
  const int wv = threadIdx.x >> 6, lane = threadIdx.x & 63;
  const int row16 = lane & 15;
  const int k0 = (lane >> 4) * 8;
  const int col = lane & 15;
  const int rb = (lane >> 4) * 4;

  // ---- phase A: rows [wv*16, wv*16+16) of act tile
  const int nodebase = blockIdx.x * 64 + wv * 16;
#pragma unroll
  for (int h = 0; h < 4; ++h) {
    const unsigned short* Ph = P + ((size_t)(nodebase + row16) * 4 + h) * 128;
    f32x4 acc[4] = {};
#pragma unroll
    for (int ks = 0; ks < 4; ++ks) {
      short8 a = *(const short8*)(Ph + ks * 32 + k0);
      const short8* bp = (const short8*)(W1p + (size_t)h * 8192) + ks * 64 + lane;
#pragma unroll
      for (int nt = 0; nt < 4; ++nt) {
        short8 b = bp[nt * 256];
        acc[nt] = __builtin_amdgcn_mfma_f32_16x16x32_bf16(a, b, acc[nt], 0, 0, 0);
      }
    }
#pragma unroll
    for (int nt = 0; nt < 4; ++nt) {
      int ch = h * 64 + nt * 16 + col;
      float bb = b1[ch];
#pragma unroll
      for (int j = 0; j < 4; ++j) {
        int row = wv * 16 + rb + j;
        float v = acc[nt][j] + bb;
        v = (v > 0.f) ? v : 0.01f * v;
        unsigned byte = (unsigned)(row * 512 + ch * 2) ^ (unsigned)((row & 7) << 4);
        *(unsigned short*)((char*)actl + byte) = f2b(v);
      }
    }
  }
  __syncthreads();

  // ---- phase B: H2 = act @ W2 (K=256) + layer-2 logits
  const int arow = wv * 16 + row16;
  f32x4 acc2[8] = {};
#pragma unroll
  for (int ks = 0; ks < 8; ++ks) {
    unsigned byte = (unsigned)(arow * 512 + (ks * 32 + k0) * 2) ^
                    (unsigned)((arow & 7) << 4);
    short8 a = *(const short8*)((const char*)actl + byte);
    const short8* bp = (const short8*)W2p + ks * 64 + lane;
#pragma unroll
    for (int nt = 0; nt < 8; ++nt) {
      short8 b = bp[(size_t)nt * 512];
      acc2[nt] = __builtin_amdgcn_mfma_f32_16x16x32_bf16(a, b, acc2[nt], 0, 0, 0);
    }
  }
  const int rbase = blockIdx.x * 64 + wv * 16 + rb;
  float av[8], dv[8];
#pragma unroll
  for (int nt = 0; nt < 8; ++nt) {
    int ch = nt * 16 + col;
    av[nt] = as2[ch];
    dv[nt] = ad2[ch];
#pragma unroll
    for (int j = 0; j < 4; ++j)
      Hout[(size_t)(rbase + j) * C2 + ch] = f2b(acc2[nt][j]);
  }
  float sa[4] = {0.f, 0.f, 0.f, 0.f}, da[4] = {0.f, 0.f, 0.f, 0.f};
#pragma unroll
  for (int nt = 0; nt < 8; ++nt)
#pragma unroll
    for (int j = 0; j < 4; ++j) {
      sa[j] += acc2[nt][j] * av[nt];
      da[j] += acc2[nt][j] * dv[nt];
    }
#pragma unroll
  for (int mask = 1; mask < 16; mask <<= 1)
#pragma unroll
    for (int j = 0; j < 4; ++j) {
      sa[j] += __shfl_xor(sa[j], mask);
      da[j] += __shfl_xor(da[j], mask);
    }
  if (col == 0) {
#pragma unroll
    for (int j = 0; j < 4; ++j) {
      als[rbase + j] = sa[j];
      ald[rbase + j] = da[j];
    }
  }
}

// ---------------- FUSED layer 2 agg + layer-3 GEMM + att3 logits -------------

__global__ __launch_bounds__(512) void k_agg2(const int* __restrict__ rowptr,
                                              const int* __restrict__ srcs,
                                              const unsigned short* __restrict__ Hm,
                                              const float* __restrict__ als,
                                              const float* __restrict__ ald,
                                              const float* __restrict__ bias,
                                              const unsigned short* __restrict__ W3p,
                                              const float* __restrict__ as3,
                                              const float* __restrict__ ad3,
                                              unsigned short* __restrict__ H3b,
                                              float* __restrict__ als3,
                                              float* __restrict__ ald3) {
  __shared__ float exs2[8][16];
  __shared__ unsigned short Xl[8][128];      // 2 KB: activated rows
  const int wv = threadIdx.x >> 6;
  const int n = blockIdx.x * 8 + wv;
  const int lane = threadIdx.x & 63;
  const int r0 = rowptr[n], r1 = rowptr[n + 1];
  const int e_lane = lane & 15;
  const int ch0 = lane * 2;
  const float aldm = ald[n];
  f32x2 accP0 = {0.f, 0.f}, accP1 = {0.f, 0.f};
  float den = 0.f;
  for (int i0 = r0; i0 < r1; i0 += 16) {
    const int take = r1 - i0;
    int sidx = srcs[min(i0 + e_lane, r1 - 1)];
    float ev = als[sidx] + aldm;
    ev = (ev > 0.f) ? ev : 0.2f * ev;
    float exv = (lane < 16 && e_lane < take) ? __expf(ev) : 0.f;
    den += exv;
    if (lane < 16) exs2[wv][lane] = exv;
    unsigned hv[16];
#pragma unroll
    for (int m = 0; m < 16; ++m) {
      int s = __builtin_amdgcn_readlane(sidx, m);
      hv[m] = *(const unsigned*)(Hm + (size_t)s * C2 + ch0);
    }
#pragma unroll
    for (int m = 0; m < 16; m += 2) {
      f32x2 ep = *(const f32x2*)(&exs2[wv][m]);
      f32x2 xa, xb;
      xa.x = __uint_as_float(hv[m] << 16);
      xa.y = __uint_as_float(hv[m + 1] << 16);
      xb.x = __uint_as_float(hv[m] & 0xffff0000u);
      xb.y = __uint_as_float(hv[m + 1] & 0xffff0000u);
      asm("v_pk_fma_f32 %0, %1, %2, %0" : "+v"(accP0) : "v"(ep), "v"(xa));
      asm("v_pk_fma_f32 %0, %1, %2, %0" : "+v"(accP1) : "v"(ep), "v"(xb));
    }
  }
#pragma unroll
  for (int mask = 1; mask < 64; mask <<= 1) den += __shfl_xor(den, mask);
  float rden = 1.f / (den + 1e-16f);
  float v0 = (accP0.x + accP0.y) * rden + bias[ch0];
  float v1 = (accP1.x + accP1.y) * rden + bias[ch0 + 1];
  v0 = (v0 > 0.f) ? v0 : 0.01f * v0;
  v1 = (v1 > 0.f) ? v1 : 0.01f * v1;
  ushort2 o; o.x = f2b(v0); o.y = f2b(v1);
  *(ushort2*)(&Xl[wv][ch0]) = o;
  __syncthreads();

  // ---- phase 2 (wave 0): 128->16 GEMM + att3 logits for the 8 nodes
  if (wv == 0) {
    const int row = lane & 15;
    const int k0 = (lane >> 4) * 8;
    const int col = lane & 15;
    f32x4 acc2 = {};
#pragma unroll
    for (int ks = 0; ks < 4; ++ks) {
      short8 a{};
      if (row < 8) a = *(const short8*)(&Xl[row][ks * 32 + k0]);
      short8 b = *((const short8*)W3p + ks * 64 + lane);
      acc2 = __builtin_amdgcn_mfma_f32_16x16x32_bf16(a, b, acc2, 0, 0, 0);
    }
    const float av = (col < C3) ? as3[col] : 0.f;
    const float dv = (col < C3) ? ad3[col] : 0.f;
    const int rb = (lane >> 4) * 4;
#pragma unroll
    for (int j = 0; j < 4; ++j) {
      float hv = acc2[j];
      float sa = hv * av, da = hv * dv;
#pragma unroll
      for (int mask = 1; mask < 16; mask <<= 1) {
        sa += __shfl_xor(sa, mask);
        da += __shfl_xor(da, mask);
      }
      int r = rb + j;
      if (r < 8) {
        int node = blockIdx.x * 8 + r;
        H3b[(size_t)node * 16 + col] = f2b(hv);
        if (col == 0) { als3[node] = sa; ald3[node] = da; }
      }
    }
  }
}

// ---------------- layer-3 aggregation + fused pool: 4 nodes/wave -------------

__global__ __launch_bounds__(512) void k_agg3(const int* __restrict__ rowptr,
                                              const int* __restrict__ srcs,
                                              const unsigned short* __restrict__ Hm,
                                              const float* __restrict__ als,
                                              const float* __restrict__ ald,
                                              const float* __restrict__ bias,
                                              float* __restrict__ pooled,
                                              const int* __restrict__ batch) {
  __shared__ int   sid_s[8][4][16];
  __shared__ float exv_s[8][4][16];
  const int wv = threadIdx.x >> 6;
  const int lane = threadIdx.x & 63;
  const int g = lane >> 4, el = lane & 15;
  const int n = blockIdx.x * 32 + wv * 4 + g;
  const bool valid = n < NNODES;
  int r0 = 0, r1 = 0;
  float aldm = 0.f;
  if (valid) { r0 = rowptr[n]; r1 = rowptr[n + 1]; aldm = ald[n]; }
  float acc = 0.f, den = 0.f;
  for (int i0 = r0; i0 < r1; i0 += 16) {
    const int take = r1 - i0;
    int sidx = srcs[min(i0 + el, r1 - 1)];
    float ev = als[sidx] + aldm;
    ev = (ev > 0.f) ? ev : 0.2f * ev;
    float exv = (el < take) ? __expf(ev) : 0.f;
    den += exv;
    sid_s[wv][g][el] = sidx;
    exv_s[wv][g][el] = exv;
#pragma unroll
    for (int m = 0; m < 16; ++m) {
      int s = sid_s[wv][g][m];
      float ex = exv_s[wv][g][m];
      acc += ex * b2f(Hm[(size_t)s * 16 + el]);
    }
  }
#pragma unroll
  for (int mask = 1; mask < 16; mask <<= 1) den += __shfl_xor(den, mask);
  if (valid && el < C3) {
    float val = acc / (den + 1e-16f) + bias[el];
    atomicAdd(&pooled[(size_t)batch[n] * C3 + el], val);
  }
}

// ---------------- log_softmax ----------------

__global__ void k_lsm(const float* __restrict__ pooled, float* __restrict__ dout) {
  int g = blockIdx.x * 256 + threadIdx.x;
  if (g >= NGRAPH) return;
  float v[C3];
  float mx = -1e30f;
#pragma unroll
  for (int c = 0; c < C3; ++c) { v[c] = pooled[g * C3 + c]; mx = fmaxf(mx, v[c]); }
  float ssum = 0.f;
#pragma unroll
  for (int c = 0; c < C3; ++c) ssum += __expf(v[c] - mx);
  float lse = mx + __logf(ssum);
#pragma unroll
  for (int c = 0; c < C3; ++c) {
    dout[g * C3 + c] = v[c] - lse;
    dout[NGRAPH * C3 + g * C3 + c] = v[c];
  }
}

// ---------------- launcher ----------------

extern "C" void kernel_launch(void* const* d_in, const int* in_sizes, int n_in,
                              void* d_out, int out_size, void* d_ws, size_t ws_size,
                              hipStream_t stream) {
  (void)in_sizes; (void)n_in; (void)out_size; (void)ws_size;
  const float* x     = (const float*)d_in[0];
  const int*   eix   = (const int*)d_in[1];
  const int*   batch = (const int*)d_in[3];
  const float* W1 = (const float*)d_in[4];
  const float* as1 = (const float*)d_in[5];
  const float* ad1 = (const float*)d_in[6];
  const float* b1 = (const float*)d_in[7];
  const float* W2 = (const float*)d_in[8];
  const float* as2 = (const float*)d_in[9];
  const float* ad2 = (const float*)d_in[10];
  const float* b2 = (const float*)d_in[11];
  const float* W3 = (const float*)d_in[12];
  const float* as3 = (const float*)d_in[13];
  const float* ad3 = (const float*)d_in[14];
  const float* b3 = (const float*)d_in[15];
  const int* src_e = eix;
  const int* dst_e = eix + NEDGE;

  char* ws = (char*)d_ws;
  size_t off = 0;
  auto carve = [&](size_t bytes) -> char* {
    char* p = ws + off;
    off += (bytes + 511) & ~(size_t)511;
    return p;
  };
  int* hists  = (int*)carve((size_t)SCM * 4);
  int* bsum   = (int*)carve((size_t)SCB * 4);
  int* cb     = (int*)carve((size_t)(NBKT + 1) * 4);
  unsigned* coarse = (unsigned*)carve((size_t)ETOT * 4);
  int* rowptr = (int*)carve((size_t)(NNODES + 1) * 4);
  int* srcs   = (int*)carve((size_t)ETOT * 4);
  float* als  = (float*)carve((size_t)MPAD * H1 * 4);
  float* ald  = (float*)carve((size_t)MPAD * H1 * 4);
  float* als3 = (float*)carve((size_t)MPAD * 4);
  float* ald3 = (float*)carve((size_t)MPAD * 4);
  float* was  = (float*)carve((size_t)512 * 4);
  float* wad  = (float*)carve((size_t)512 * 4);
  unsigned short* Xb  = (unsigned short*)carve((size_t)MPAD * 128 * 2);
  unsigned short* P   = (unsigned short*)carve((size_t)MPAD * 512 * 2);
  unsigned short* Hb  = (unsigned short*)carve((size_t)MPAD * 128 * 2);
  unsigned short* H3b = (unsigned short*)carve((size_t)MPAD * 16 * 2);
  float* pooled = (float*)carve((size_t)NGRAPH * C3 * 4);
  unsigned short* W1p = (unsigned short*)carve((size_t)4 * 8192 * 2);
  unsigned short* W2p = (unsigned short*)carve((size_t)O1 * C2 * 2);
  unsigned short* W3p = (unsigned short*)carve((size_t)C2 * 16 * 2);

  hipMemsetAsync(pooled, 0, (size_t)NGRAPH * C3 * 4, stream);

  // prep FIRST (k_front's cvt blocks read was/wad)
  k_prep<<<1, 512, 0, stream>>>(W1, as1, ad1, was, wad);
  // fused: coarse histogram + cvt/logits + weight packs
  k_front<<<NBLK1 + NB_CVT + 264, 256, 0, stream>>>(
      src_e, dst_e, hists, x, Xb, W1, was, wad, als, ald, W1p, W2, W2p, W3, W3p);
  // exclusive scan of the (bin, block) offset table; emits coarse bases cb
  k_scanA2<<<SCB, 256, 0, stream>>>(hists, bsum);
  k_scanMid<<<1, 256, 0, stream>>>(bsum);
  k_scanB2<<<SCB, 256, 0, stream>>>(hists, bsum, cb);
  // partition edges into coarse buckets, then fine-bin -> rowptr + srcs
  k_part1<<<NBLK1, 256, 0, stream>>>(src_e, dst_e, hists, coarse);
  k_bucket<<<NBKT, 256, 0, stream>>>(coarse, cb, rowptr, srcs);

  const int GB = MPAD / 64;        // 782 gemm blocks
  const int NB8 = NNODES / 8;      // 6250 agg blocks
  const int NB32 = (NNODES + 31) / 32;   // 1563 agg3 blocks (4 nodes/wave)

  // layer 1: aggregate X^ in the 128-ch basis (4 heads) -> P (global)
  k_aggP<<<NB8, 512, 0, stream>>>(rowptr, srcs, Xb, als, ald, P);
  // fused GEMM chain: P@W1 -> lrelu -> @W2 -> Hb + layer-2 logits
  k_mmX<<<GB, 256, 0, stream>>>(P, W1p, b1, W2p, as2, ad2, Hb, als, ald);

  // layer 2 agg fused with layer-3 GEMM + logits
  k_agg2<<<NB8, 512, 0, stream>>>(rowptr, srcs, Hb, als, ald, b2,
                                  W3p, as3, ad3, H3b, als3, ald3);

  // layer 3: aggregate + fused pool
  k_agg3<<<NB32, 512, 0, stream>>>(rowptr, srcs, H3b, als3, ald3, b3, pooled, batch);

  // log_softmax; output = [log_softmax | pooled]
  k_lsm<<<(NGRAPH + 255) / 256, 256, 0, stream>>>(pooled, (float*)d_out);
}

// Round 14
// 213.063 us; speedup vs baseline: 1.0677x; 1.0421x over previous
//
#include <hip/hip_runtime.h>
#include <math.h>

#define NNODES 50000
#define MPAD   50048            // 782 * 64
#define NFEAT  128
#define NEDGE  800000
#define ETOT   (NEDGE + NNODES) // 850000 edges incl. self-loops
#define H1     4
#define O1     256              // heads1 * hid1
#define C2     128
#define C3     10
#define NGRAPH 512

#define NBKT   196              // coarse buckets: dst >> 8
#define NBLK1  831              // 831*1024 >= ETOT
#define EPB    1024             // edges per hist/partition block
#define SCM    (NBKT * NBLK1)   // 162876 offset-table entries
#define SCB    637              // ceil(SCM/256)

typedef __attribute__((ext_vector_type(8))) short short8;
typedef __attribute__((ext_vector_type(4))) float f32x4;
typedef __attribute__((ext_vector_type(2))) float f32x2;

__device__ __forceinline__ unsigned short f2b(float f) {
  unsigned int u = __float_as_uint(f);
  u += 0x7fffu + ((u >> 16) & 1u);
  return (unsigned short)(u >> 16);
}
__device__ __forceinline__ float b2f(unsigned short u) {
  return __uint_as_float(((unsigned int)u) << 16);
}
__device__ __forceinline__ float readlane_f(float v, int l) {
  return __uint_as_float((unsigned)__builtin_amdgcn_readlane(__float_as_uint(v), l));
}

// ---------------- layer-1 prep + pooled zeroing (runs before k_front) --------

__global__ void k_prep(const float* __restrict__ W1, const float* __restrict__ as1,
                       const float* __restrict__ ad1,
                       float* __restrict__ was, float* __restrict__ wad,
                       float* __restrict__ pooled) {
  int tid = threadIdx.x;          // 512 = 4 heads x 128 k
  for (int i = tid; i < NGRAPH * C3; i += 512) pooled[i] = 0.f;
  int h = tid >> 7, k = tid & 127;
  float s = 0.f, d = 0.f;
  for (int j = 0; j < 64; ++j) {
    float w = W1[(size_t)k * 256 + h * 64 + j];
    s += w * as1[h * 64 + j];
    d += w * ad1[h * 64 + j];
  }
  was[h * 128 + k] = s;
  wad[h * 128 + k] = d;
}

// ---------------- fused front kernel ----------------
#define NB_CVT 12500

__global__ __launch_bounds__(256) void k_front(
    const int* __restrict__ src_e, const int* __restrict__ dst_e,
    int* __restrict__ hists,
    const float* __restrict__ X, unsigned short* __restrict__ Xb,
    const float* __restrict__ W1,
    const float* __restrict__ was, const float* __restrict__ wad,
    float* __restrict__ als, float* __restrict__ ald,
    unsigned short* __restrict__ W1p,
    const float* __restrict__ W2, unsigned short* __restrict__ W2p,
    const float* __restrict__ W3, unsigned short* __restrict__ W3p) {
  const int b = blockIdx.x;
  const int tid = threadIdx.x;
  if (b < NBLK1) {                           // ---- coarse histogram (LDS only)
    __shared__ int h[NBKT];
    if (tid < NBKT) h[tid] = 0;
    __syncthreads();
    const int base = b * EPB;
#pragma unroll
    for (int r = 0; r < 4; ++r) {
      int e = base + r * 256 + tid;
      if (e < ETOT) {
        int d = (e < NEDGE) ? dst_e[e] : (e - NEDGE);
        atomicAdd(&h[d >> 8], 1);
      }
    }
    __syncthreads();
    if (tid < NBKT) hists[tid * NBLK1 + b] = h[tid];
  } else if (b < NBLK1 + NB_CVT) {           // ---- cvt X->bf16 + layer-1 logits
    const int n = (b - NBLK1) * 4 + (tid >> 6);
    const int lane = tid & 63;
    const int k0 = lane * 2;
    float2 xv = *(const float2*)(X + (size_t)n * 128 + k0);
    ushort2 o; o.x = f2b(xv.x); o.y = f2b(xv.y);
    *(ushort2*)(Xb + (size_t)n * 128 + k0) = o;
    float s[4], d[4];
#pragma unroll
    for (int h = 0; h < 4; ++h) {
      float2 wsv = *(const float2*)(was + h * 128 + k0);
      float2 wdv = *(const float2*)(wad + h * 128 + k0);
      s[h] = xv.x * wsv.x + xv.y * wsv.y;
      d[h] = xv.x * wdv.x + xv.y * wdv.y;
    }
#pragma unroll
    for (int m = 1; m < 64; m <<= 1)
#pragma unroll
      for (int h = 0; h < 4; ++h) { s[h] += __shfl_xor(s[h], m); d[h] += __shfl_xor(d[h], m); }
    if (lane == 0) {
#pragma unroll
      for (int h = 0; h < 4; ++h) {
        als[(size_t)n * 4 + h] = s[h];
        ald[(size_t)n * 4 + h] = d[h];
      }
    }
  } else if (b < NBLK1 + NB_CVT + 128) {     // ---- pack W1 per head
    int idx = (b - NBLK1 - NB_CVT) * 256 + tid;   // 4*8192
    int h = idx >> 13, r = idx & 8191;
    int j = r & 7, lane = (r >> 3) & 63, t = r >> 9;
    int ks = t & 3, nt = t >> 2;
    int k = ks * 32 + (lane >> 4) * 8 + j;
    int n = nt * 16 + (lane & 15);
    W1p[idx] = f2b(W1[(size_t)k * 256 + h * 64 + n]);
  } else if (b < NBLK1 + NB_CVT + 256) {     // ---- pack W2 (K=256,N=128)
    int idx = (b - NBLK1 - NB_CVT - 128) * 256 + tid;  // 32768
    int j = idx & 7, lane = (idx >> 3) & 63, t = idx >> 9;
    int ks = t % 8, nt = t / 8;
    int k = ks * 32 + (lane >> 4) * 8 + j;
    int n = nt * 16 + (lane & 15);
    W2p[idx] = f2b(W2[(size_t)k * C2 + n]);
  } else {                                    // ---- pack W3 (K=128,N=16,real 10)
    int idx = (b - NBLK1 - NB_CVT - 256) * 256 + tid;  // 2048
    int j = idx & 7, lane = (idx >> 3) & 63, t = idx >> 9;
    int ks = t & 3, nt = t >> 2;
    int k = ks * 32 + (lane >> 4) * 8 + j;
    int n = nt * 16 + (lane & 15);
    W3p[idx] = f2b((n < C3) ? W3[(size_t)k * C3 + n] : 0.f);
  }
}

// ---------------- offset-table scan (exclusive, over SCM ints) ----------------

__global__ __launch_bounds__(256) void k_scanA2(const int* __restrict__ a,
                                                int* __restrict__ bsum) {
  int idx = blockIdx.x * 256 + threadIdx.x;
  int v = (idx < SCM) ? a[idx] : 0;
#pragma unroll
  for (int m = 1; m < 64; m <<= 1) v += __shfl_xor(v, m);
  __shared__ int ws[4];
  int lane = threadIdx.x & 63, wid = threadIdx.x >> 6;
  if (lane == 0) ws[wid] = v;
  __syncthreads();
  if (threadIdx.x == 0) bsum[blockIdx.x] = ws[0] + ws[1] + ws[2] + ws[3];
}

// scanB2 now also computes its own block-prefix over bsum (scanMid folded in)
__global__ __launch_bounds__(256) void k_scanB2(int* __restrict__ a,
                                                const int* __restrict__ bsum,
                                                int* __restrict__ cb) {
  const int b = blockIdx.x, tid = threadIdx.x;
  const int lane = tid & 63, wid = tid >> 6;
  __shared__ int ws[4];
  __shared__ int ws2[4];
  // boff = sum of bsum[0..b)
  int part = 0;
  for (int i0 = 0; i0 < SCB; i0 += 256) {
    int i = i0 + tid;
    if (i < b) part += bsum[i];
  }
#pragma unroll
  for (int m = 1; m < 64; m <<= 1) part += __shfl_xor(part, m);
  if (lane == 0) ws2[wid] = part;
  __syncthreads();
  const int boff = ws2[0] + ws2[1] + ws2[2] + ws2[3];
  // per-element exclusive scan of this 256-chunk
  int idx = b * 256 + tid;
  int v = (idx < SCM) ? a[idx] : 0;
  int s = v;
#pragma unroll
  for (int m = 1; m < 64; m <<= 1) {
    int t = __shfl_up(s, m);
    if (lane >= m) s += t;
  }
  if (lane == 63) ws[wid] = s;
  __syncthreads();
  int woff = 0;
#pragma unroll
  for (int k = 0; k < 4; ++k)
    if (k < wid) woff += ws[k];
  int excl = boff + woff + s - v;
  if (idx < SCM) {
    a[idx] = excl;
    if (idx % NBLK1 == 0) cb[idx / NBLK1] = excl;   // coarse bucket base
  }
  if (b == 0 && tid == 0) cb[NBKT] = ETOT;
}

// ---------------- partition into coarse buckets (LDS atomics only) ----------

__global__ __launch_bounds__(256) void k_part1(const int* __restrict__ src_e,
                                               const int* __restrict__ dst_e,
                                               const int* __restrict__ offs,
                                               unsigned* __restrict__ coarse) {
  __shared__ int cur[NBKT];
  const int b = blockIdx.x;
  const int tid = threadIdx.x;
  if (tid < NBKT) cur[tid] = offs[tid * NBLK1 + b];
  __syncthreads();
  const int base = b * EPB;
#pragma unroll
  for (int r = 0; r < 4; ++r) {
    int e = base + r * 256 + tid;
    if (e < ETOT) {
      int d, s;
      if (e < NEDGE) { d = dst_e[e]; s = src_e[e]; }
      else           { d = e - NEDGE; s = e - NEDGE; }
      int pos = atomicAdd(&cur[d >> 8], 1);
      coarse[pos] = ((unsigned)d << 16) | (unsigned)s;
    }
  }
}

// ---------------- per-bucket fine binning -> rowptr + srcs -------------------

__global__ __launch_bounds__(256) void k_bucket(const unsigned* __restrict__ coarse,
                                                const int* __restrict__ cb,
                                                int* __restrict__ rowptr,
                                                int* __restrict__ srcs) {
  const int b = blockIdx.x;                  // 196 buckets
  const int tid = threadIdx.x;
  const int lane = tid & 63, wid = tid >> 6;
  const int lo = cb[b], hi = cb[b + 1];
  __shared__ int h[256];
  __shared__ int cur[256];
  __shared__ int ws[4];
  h[tid] = 0;
  __syncthreads();
  for (int i = lo + tid; i < hi; i += 256)
    atomicAdd(&h[(coarse[i] >> 16) & 255], 1);
  __syncthreads();
  int v = h[tid];
  int s = v;
#pragma unroll
  for (int m = 1; m < 64; m <<= 1) {
    int t = __shfl_up(s, m);
    if (lane >= m) s += t;
  }
  if (lane == 63) ws[wid] = s;
  __syncthreads();
  int woff = 0;
#pragma unroll
  for (int k = 0; k < 4; ++k)
    if (k < wid) woff += ws[k];
  int ex = woff + s - v;                     // exclusive fine scan
  cur[tid] = lo + ex;
  int d = b * 256 + tid;
  if (d < NNODES) rowptr[d] = lo + ex;
  if (b == NBKT - 1 && tid == 0) rowptr[NNODES] = ETOT;
  __syncthreads();
  for (int i = lo + tid; i < hi; i += 256) {
    unsigned c = coarse[i];
    int pos = atomicAdd(&cur[(c >> 16) & 255], 1);
    srcs[pos] = (int)(c & 0xffffu);
  }
}

// ---------------- layer-1 pre-GEMM aggregation (128 ch, 4 heads) ----

__global__ __launch_bounds__(512) void k_aggP(const int* __restrict__ rowptr,
                                              const int* __restrict__ srcs,
                                              const unsigned short* __restrict__ Xb,
                                              const float* __restrict__ als,
                                              const float* __restrict__ ald,
                                              unsigned short* __restrict__ P) {
  __shared__ float exs[8][16][4];           // [wave][edge][head]
  const int wv = threadIdx.x >> 6;
  const int n = blockIdx.x * 8 + wv;
  const int lane = threadIdx.x & 63;
  const int r0 = rowptr[n], r1 = rowptr[n + 1];
  const int e_lane = lane & 15, hh = lane >> 4;
  const float aldv = ald[(size_t)n * 4 + hh];
  const int ch0 = lane * 2;
  f32x2 ah0 = {0.f, 0.f}, ah1 = {0.f, 0.f}, ah2 = {0.f, 0.f}, ah3 = {0.f, 0.f};
  float den = 0.f;
  for (int i0 = r0; i0 < r1; i0 += 16) {
    const int take = r1 - i0;
    int sidx = srcs[min(i0 + e_lane, r1 - 1)];
    float ev = als[(size_t)sidx * 4 + hh] + aldv;
    ev = (ev > 0.f) ? ev : 0.2f * ev;
    float exv = (e_lane < take) ? __expf(ev) : 0.f;
    den += exv;
    exs[wv][e_lane][hh] = exv;
    unsigned hv[16];
#pragma unroll
    for (int m = 0; m < 16; ++m) {
      int s = __builtin_amdgcn_readlane(sidx, m);
      hv[m] = *(const unsigned*)(Xb + (size_t)s * 128 + ch0);
    }
#pragma unroll
    for (int m = 0; m < 16; ++m) {
      f32x2 e01 = *(const f32x2*)(&exs[wv][m][0]);
      f32x2 e23 = *(const f32x2*)(&exs[wv][m][2]);
      f32x2 x2;
      x2.x = __uint_as_float(hv[m] << 16);
      x2.y = __uint_as_float(hv[m] & 0xffff0000u);
      asm("v_pk_fma_f32 %0, %1, %2, %0 op_sel:[0,0,0] op_sel_hi:[1,0,1]"
          : "+v"(ah0) : "v"(x2), "v"(e01));
      asm("v_pk_fma_f32 %0, %1, %2, %0 op_sel:[0,1,0] op_sel_hi:[1,1,1]"
          : "+v"(ah1) : "v"(x2), "v"(e01));
      asm("v_pk_fma_f32 %0, %1, %2, %0 op_sel:[0,0,0] op_sel_hi:[1,0,1]"
          : "+v"(ah2) : "v"(x2), "v"(e23));
      asm("v_pk_fma_f32 %0, %1, %2, %0 op_sel:[0,1,0] op_sel_hi:[1,1,1]"
          : "+v"(ah3) : "v"(x2), "v"(e23));
    }
  }
#pragma unroll
  for (int m = 1; m < 16; m <<= 1) den += __shfl_xor(den, m);
  float acc[4][2] = {{ah0.x, ah0.y}, {ah1.x, ah1.y}, {ah2.x, ah2.y}, {ah3.x, ah3.y}};
#pragma unroll
  for (int h = 0; h < 4; ++h) {
    float rd = 1.f / (readlane_f(den, h * 16) + 1e-16f);
    ushort2 o; o.x = f2b(acc[h][0] * rd); o.y = f2b(acc[h][1] * rd);
    *(ushort2*)(P + ((size_t)n * 4 + h) * 128 + ch0) = o;
  }
}

// ---------------- FUSED GEMM chain: act1 = lrelu(P@W1+b1); H2 = act1@W2 ------

__global__ __launch_bounds__(256) void k_mmX(
    const unsigned short* __restrict__ P,
    const unsigned short* __restrict__ W1p, const float* __restrict__ b1,
    const unsigned short* __restrict__ W2p,
    const float* __restrict__ as2, const float* __restrict__ ad2,
    unsigned short* __restrict__ Hout,
    float* __restrict__ als, float* __restrict__ ald) {
  __shared__ unsigned short actl[64 * 256];   // 32 KB
  const int wv = threadIdx.x >> 6, lane = threadIdx.x & 63;
  const int row16 = lane & 15;
  const int k0 = (lane >> 4) * 8;
  const int col = lane & 15;
  const int rb = (lane >> 4) * 4;

  // ---- phase A: rows [wv*16, wv*16+16) of act tile
  const int nodebase = blockIdx.x * 64 + wv * 16;
#pragma unroll
  for (int h = 0; h < 4; ++h) {
    const unsigned short* Ph = P + ((size_t)(nodebase + row16) * 4 + h) * 128;
    f32x4 acc[4] = {};
#pragma unroll
    for (int ks = 0; ks < 4; ++ks) {
      short8 a = *(const short8*)(Ph + ks * 32 + k0);
      const short8* bp = (const short8*)(W1p + (size_t)h * 8192) + ks * 64 + lane;
#pragma unroll
      for (int nt = 0; nt < 4; ++nt) {
        short8 b = bp[nt * 256];
        acc[nt] = __builtin_amdgcn_mfma_f32_16x16x32_bf16(a, b, acc[nt], 0, 0, 0);
      }
    }
#pragma unroll
    for (int nt = 0; nt < 4; ++nt) {
      int ch = h * 64 + nt * 16 + col;
      float bb = b1[ch];
#pragma unroll
      for (int j = 0; j < 4; ++j) {
        int row = wv * 16 + rb + j;
        float v = acc[nt][j] + bb;
        v = (v > 0.f) ? v : 0.01f * v;
        unsigned byte = (unsigned)(row * 512 + ch * 2) ^ (unsigned)((row & 7) << 4);
        *(unsigned short*)((char*)actl + byte) = f2b(v);
      }
    }
  }
  __syncthreads();

  // ---- phase B: H2 = act @ W2 (K=256) + layer-2 logits
  const int arow = wv * 16 + row16;
  f32x4 acc2[8] = {};
#pragma unroll
  for (int ks = 0; ks < 8; ++ks) {
    unsigned byte = (unsigned)(arow * 512 + (ks * 32 + k0) * 2) ^
                    (unsigned)((arow & 7) << 4);
    short8 a = *(const short8*)((const char*)actl + byte);
    const short8* bp = (const short8*)W2p + ks * 64 + lane;
#pragma unroll
    for (int nt = 0; nt < 8; ++nt) {
      short8 b = bp[(size_t)nt * 512];
      acc2[nt] = __builtin_amdgcn_mfma_f32_16x16x32_bf16(a, b, acc2[nt], 0, 0, 0);
    }
  }
  const int rbase = blockIdx.x * 64 + wv * 16 + rb;
  float av[8], dv[8];
#pragma unroll
  for (int nt = 0; nt < 8; ++nt) {
    int ch = nt * 16 + col;
    av[nt] = as2[ch];
    dv[nt] = ad2[ch];
#pragma unroll
    for (int j = 0; j < 4; ++j)
      Hout[(size_t)(rbase + j) * C2 + ch] = f2b(acc2[nt][j]);
  }
  float sa[4] = {0.f, 0.f, 0.f, 0.f}, da[4] = {0.f, 0.f, 0.f, 0.f};
#pragma unroll
  for (int nt = 0; nt < 8; ++nt)
#pragma unroll
    for (int j = 0; j < 4; ++j) {
      sa[j] += acc2[nt][j] * av[nt];
      da[j] += acc2[nt][j] * dv[nt];
    }
#pragma unroll
  for (int mask = 1; mask < 16; mask <<= 1)
#pragma unroll
    for (int j = 0; j < 4; ++j) {
      sa[j] += __shfl_xor(sa[j], mask);
      da[j] += __shfl_xor(da[j], mask);
    }
  if (col == 0) {
#pragma unroll
    for (int j = 0; j < 4; ++j) {
      als[rbase + j] = sa[j];
      ald[rbase + j] = da[j];
    }
  }
}

// ---------------- FUSED layer 2 agg + per-wave layer-3 GEMM + att3 logits ----
// Phase 1: aggregation over Hb (edge-paired pk_fma), bias + lrelu -> private
// LDS slice. Phase 2 (SAME wave, no barrier): broadcast-read own row as a
// replicated A operand, 4 MFMAs @ W3p -> H3b + als3/ald3.

__global__ __launch_bounds__(512) void k_agg2(const int* __restrict__ rowptr,
                                              const int* __restrict__ srcs,
                                              const unsigned short* __restrict__ Hm,
                                              const float* __restrict__ als,
                                              const float* __restrict__ ald,
                                              const float* __restrict__ bias,
                                              const unsigned short* __restrict__ W3p,
                                              const float* __restrict__ as3,
                                              const float* __restrict__ ad3,
                                              unsigned short* __restrict__ H3b,
                                              float* __restrict__ als3,
                                              float* __restrict__ ald3) {
  __shared__ float exs2[8][16];
  __shared__ unsigned short Xl[8][128];      // 2 KB: activated rows (per-wave slice)
  const int wv = threadIdx.x >> 6;
  const int n = blockIdx.x * 8 + wv;
  const int lane = threadIdx.x & 63;
  const int r0 = rowptr[n], r1 = rowptr[n + 1];
  const int e_lane = lane & 15;
  const int ch0 = lane * 2;
  const float aldm = ald[n];
  f32x2 accP0 = {0.f, 0.f}, accP1 = {0.f, 0.f};
  float den = 0.f;
  for (int i0 = r0; i0 < r1; i0 += 16) {
    const int take = r1 - i0;
    int sidx = srcs[min(i0 + e_lane, r1 - 1)];
    float ev = als[sidx] + aldm;
    ev = (ev > 0.f) ? ev : 0.2f * ev;
    float exv = (lane < 16 && e_lane < take) ? __expf(ev) : 0.f;
    den += exv;
    if (lane < 16) exs2[wv][lane] = exv;
    unsigned hv[16];
#pragma unroll
    for (int m = 0; m < 16; ++m) {
      int s = __builtin_amdgcn_readlane(sidx, m);
      hv[m] = *(const unsigned*)(Hm + (size_t)s * C2 + ch0);
    }
#pragma unroll
    for (int m = 0; m < 16; m += 2) {
      f32x2 ep = *(const f32x2*)(&exs2[wv][m]);
      f32x2 xa, xb;
      xa.x = __uint_as_float(hv[m] << 16);
      xa.y = __uint_as_float(hv[m + 1] << 16);
      xb.x = __uint_as_float(hv[m] & 0xffff0000u);
      xb.y = __uint_as_float(hv[m + 1] & 0xffff0000u);
      asm("v_pk_fma_f32 %0, %1, %2, %0" : "+v"(accP0) : "v"(ep), "v"(xa));
      asm("v_pk_fma_f32 %0, %1, %2, %0" : "+v"(accP1) : "v"(ep), "v"(xb));
    }
  }
#pragma unroll
  for (int mask = 1; mask < 64; mask <<= 1) den += __shfl_xor(den, mask);
  float rden = 1.f / (den + 1e-16f);
  float v0 = (accP0.x + accP0.y) * rden + bias[ch0];
  float v1 = (accP1.x + accP1.y) * rden + bias[ch0 + 1];
  v0 = (v0 > 0.f) ? v0 : 0.01f * v0;
  v1 = (v1 > 0.f) ? v1 : 0.01f * v1;
  ushort2 o; o.x = f2b(v0); o.y = f2b(v1);
  *(ushort2*)(&Xl[wv][ch0]) = o;
  // same-wave LDS write -> read ordering (no block barrier needed)
  asm volatile("s_waitcnt lgkmcnt(0)" ::: "memory");

  // ---- phase 2 (per wave): replicated-A 128->16 GEMM + att3 logits
  const int k0 = (lane >> 4) * 8;
  const int col = lane & 15;
  f32x4 acc2 = {};
#pragma unroll
  for (int ks = 0; ks < 4; ++ks) {
    short8 a = *(const short8*)(&Xl[wv][ks * 32 + k0]);  // broadcast: rows replicated
    short8 b = *((const short8*)W3p + ks * 64 + lane);
    acc2 = __builtin_amdgcn_mfma_f32_16x16x32_bf16(a, b, acc2, 0, 0, 0);
  }
  float hv = acc2[0];                        // all C rows equal; col = lane&15
  const float av = (col < C3) ? as3[col] : 0.f;
  const float dv = (col < C3) ? ad3[col] : 0.f;
  float sa = hv * av, da = hv * dv;
#pragma unroll
  for (int mask = 1; mask < 16; mask <<= 1) {
    sa += __shfl_xor(sa, mask);
    da += __shfl_xor(da, mask);
  }
  if (lane < 16) H3b[(size_t)n * 16 + col] = f2b(hv);
  if (lane == 0) { als3[n] = sa; ald3[n] = da; }
}

// ---------------- layer-3 aggregation + fused pool: 4 nodes/wave -------------

__global__ __launch_bounds__(512) void k_agg3(const int* __restrict__ rowptr,
                                              const int* __restrict__ srcs,
                                              const unsigned short* __restrict__ Hm,
                                              const float* __restrict__ als,
                                              const float* __restrict__ ald,
                                              const float* __restrict__ bias,
                                              float* __restrict__ pooled,
                                              const int* __restrict__ batch) {
  __shared__ int   sid_s[8][4][16];
  __shared__ float exv_s[8][4][16];
  const int wv = threadIdx.x >> 6;
  const int lane = threadIdx.x & 63;
  const int g = lane >> 4, el = lane & 15;
  const int n = blockIdx.x * 32 + wv * 4 + g;
  const bool valid = n < NNODES;
  int r0 = 0, r1 = 0;
  float aldm = 0.f;
  if (valid) { r0 = rowptr[n]; r1 = rowptr[n + 1]; aldm = ald[n]; }
  float acc = 0.f, den = 0.f;
  for (int i0 = r0; i0 < r1; i0 += 16) {
    const int take = r1 - i0;
    int sidx = srcs[min(i0 + el, r1 - 1)];
    float ev = als[sidx] + aldm;
    ev = (ev > 0.f) ? ev : 0.2f * ev;
    float exv = (el < take) ? __expf(ev) : 0.f;
    den += exv;
    sid_s[wv][g][el] = sidx;
    exv_s[wv][g][el] = exv;
#pragma unroll
    for (int m = 0; m < 16; ++m) {
      int s = sid_s[wv][g][m];
      float ex = exv_s[wv][g][m];
      acc += ex * b2f(Hm[(size_t)s * 16 + el]);
    }
  }
#pragma unroll
  for (int mask = 1; mask < 16; mask <<= 1) den += __shfl_xor(den, mask);
  if (valid && el < C3) {
    float val = acc / (den + 1e-16f) + bias[el];
    atomicAdd(&pooled[(size_t)batch[n] * C3 + el], val);
  }
}

// ---------------- log_softmax ----------------

__global__ void k_lsm(const float* __restrict__ pooled, float* __restrict__ dout) {
  int g = blockIdx.x * 256 + threadIdx.x;
  if (g >= NGRAPH) return;
  float v[C3];
  float mx = -1e30f;
#pragma unroll
  for (int c = 0; c < C3; ++c) { v[c] = pooled[g * C3 + c]; mx = fmaxf(mx, v[c]); }
  float ssum = 0.f;
#pragma unroll
  for (int c = 0; c < C3; ++c) ssum += __expf(v[c] - mx);
  float lse = mx + __logf(ssum);
#pragma unroll
  for (int c = 0; c < C3; ++c) {
    dout[g * C3 + c] = v[c] - lse;
    dout[NGRAPH * C3 + g * C3 + c] = v[c];
  }
}

// ---------------- launcher ----------------

extern "C" void kernel_launch(void* const* d_in, const int* in_sizes, int n_in,
                              void* d_out, int out_size, void* d_ws, size_t ws_size,
                              hipStream_t stream) {
  (void)in_sizes; (void)n_in; (void)out_size; (void)ws_size;
  const float* x     = (const float*)d_in[0];
  const int*   eix   = (const int*)d_in[1];
  const int*   batch = (const int*)d_in[3];
  const float* W1 = (const float*)d_in[4];
  const float* as1 = (const float*)d_in[5];
  const float* ad1 = (const float*)d_in[6];
  const float* b1 = (const float*)d_in[7];
  const float* W2 = (const float*)d_in[8];
  const float* as2 = (const float*)d_in[9];
  const float* ad2 = (const float*)d_in[10];
  const float* b2 = (const float*)d_in[11];
  const float* W3 = (const float*)d_in[12];
  const float* as3 = (const float*)d_in[13];
  const float* ad3 = (const float*)d_in[14];
  const float* b3 = (const float*)d_in[15];
  const int* src_e = eix;
  const int* dst_e = eix + NEDGE;

  char* ws = (char*)d_ws;
  size_t off = 0;
  auto carve = [&](size_t bytes) -> char* {
    char* p = ws + off;
    off += (bytes + 511) & ~(size_t)511;
    return p;
  };
  int* hists  = (int*)carve((size_t)SCM * 4);
  int* bsum   = (int*)carve((size_t)SCB * 4);
  int* cb     = (int*)carve((size_t)(NBKT + 1) * 4);
  unsigned* coarse = (unsigned*)carve((size_t)ETOT * 4);
  int* rowptr = (int*)carve((size_t)(NNODES + 1) * 4);
  int* srcs   = (int*)carve((size_t)ETOT * 4);
  float* als  = (float*)carve((size_t)MPAD * H1 * 4);
  float* ald  = (float*)carve((size_t)MPAD * H1 * 4);
  float* als3 = (float*)carve((size_t)MPAD * 4);
  float* ald3 = (float*)carve((size_t)MPAD * 4);
  float* was  = (float*)carve((size_t)512 * 4);
  float* wad  = (float*)carve((size_t)512 * 4);
  unsigned short* Xb  = (unsigned short*)carve((size_t)MPAD * 128 * 2);
  unsigned short* P   = (unsigned short*)carve((size_t)MPAD * 512 * 2);
  unsigned short* Hb  = (unsigned short*)carve((size_t)MPAD * 128 * 2);
  unsigned short* H3b = (unsigned short*)carve((size_t)MPAD * 16 * 2);
  float* pooled = (float*)carve((size_t)NGRAPH * C3 * 4);
  unsigned short* W1p = (unsigned short*)carve((size_t)4 * 8192 * 2);
  unsigned short* W2p = (unsigned short*)carve((size_t)O1 * C2 * 2);
  unsigned short* W3p = (unsigned short*)carve((size_t)C2 * 16 * 2);

  // prep FIRST (k_front's cvt blocks read was/wad); also zeroes pooled
  k_prep<<<1, 512, 0, stream>>>(W1, as1, ad1, was, wad, pooled);
  // fused: coarse histogram + cvt/logits + weight packs
  k_front<<<NBLK1 + NB_CVT + 264, 256, 0, stream>>>(
      src_e, dst_e, hists, x, Xb, W1, was, wad, als, ald, W1p, W2, W2p, W3, W3p);
  // exclusive scan of the (bin, block) offset table; emits coarse bases cb
  k_scanA2<<<SCB, 256, 0, stream>>>(hists, bsum);
  k_scanB2<<<SCB, 256, 0, stream>>>(hists, bsum, cb);
  // partition edges into coarse buckets, then fine-bin -> rowptr + srcs
  k_part1<<<NBLK1, 256, 0, stream>>>(src_e, dst_e, hists, coarse);
  k_bucket<<<NBKT, 256, 0, stream>>>(coarse, cb, rowptr, srcs);

  const int GB = MPAD / 64;        // 782 gemm blocks
  const int NB8 = NNODES / 8;      // 6250 agg blocks
  const int NB32 = (NNODES + 31) / 32;   // 1563 agg3 blocks (4 nodes/wave)

  // layer 1: aggregate X^ in the 128-ch basis (4 heads) -> P (global)
  k_aggP<<<NB8, 512, 0, stream>>>(rowptr, srcs, Xb, als, ald, P);
  // fused GEMM chain: P@W1 -> lrelu -> @W2 -> Hb + layer-2 logits
  k_mmX<<<GB, 256, 0, stream>>>(P, W1p, b1, W2p, as2, ad2, Hb, als, ald);

  // layer 2 agg fused with per-wave layer-3 GEMM + logits (no barrier)
  k_agg2<<<NB8, 512, 0, stream>>>(rowptr, srcs, Hb, als, ald, b2,
                                  W3p, as3, ad3, H3b, als3, ald3);

  // layer 3: aggregate + fused pool
  k_agg3<<<NB32, 512, 0, stream>>>(rowptr, srcs, H3b, als3, ald3, b3, pooled, batch);

  // log_softmax; output = [log_softmax | pooled]
  k_lsm<<<(NGRAPH + 255) / 256, 256, 0, stream>>>(pooled, (float*)d_out);
}

// Round 15
// 207.032 us; speedup vs baseline: 1.0988x; 1.0291x over previous
//
#include <hip/hip_runtime.h>
#include <math.h>

#define NNODES 50000
#define MPAD   50048            // 782 * 64
#define NFEAT  128
#define NEDGE  800000
#define ETOT   (NEDGE + NNODES) // 850000 edges incl. self-loops
#define H1     4
#define O1     256              // heads1 * hid1
#define C2     128
#define C3     10
#define NGRAPH 512

#define NBKT   196              // coarse buckets: dst >> 8
#define NBLK1  831              // 831*1024 >= ETOT
#define EPB    1024             // edges per hist/partition block
#define SCM    (NBKT * NBLK1)   // 162876 offset-table entries
#define SCB    637              // ceil(SCM/256)

typedef __attribute__((ext_vector_type(8))) short short8;
typedef __attribute__((ext_vector_type(4))) float f32x4;
typedef __attribute__((ext_vector_type(2))) float f32x2;

__device__ __forceinline__ unsigned short f2b(float f) {
  unsigned int u = __float_as_uint(f);
  u += 0x7fffu + ((u >> 16) & 1u);
  return (unsigned short)(u >> 16);
}
__device__ __forceinline__ float b2f(unsigned short u) {
  return __uint_as_float(((unsigned int)u) << 16);
}
__device__ __forceinline__ float readlane_f(float v, int l) {
  return __uint_as_float((unsigned)__builtin_amdgcn_readlane(__float_as_uint(v), l));
}

// ---------------- layer-1 prep + pooled zeroing (runs before k_front) --------

__global__ void k_prep(const float* __restrict__ W1, const float* __restrict__ as1,
                       const float* __restrict__ ad1,
                       float* __restrict__ was, float* __restrict__ wad,
                       float* __restrict__ pooled) {
  int tid = threadIdx.x;          // 512 = 4 heads x 128 k
  for (int i = tid; i < NGRAPH * C3; i += 512) pooled[i] = 0.f;
  int h = tid >> 7, k = tid & 127;
  float s = 0.f, d = 0.f;
  for (int j = 0; j < 64; ++j) {
    float w = W1[(size_t)k * 256 + h * 64 + j];
    s += w * as1[h * 64 + j];
    d += w * ad1[h * 64 + j];
  }
  was[h * 128 + k] = s;
  wad[h * 128 + k] = d;
}

// ---------------- fused front kernel ----------------
// cvt: 32 nodes/block, 8 lanes per node (3-round shfl reduce)
#define NB_CVT 1563             // ceil(NNODES/32)

__global__ __launch_bounds__(256) void k_front(
    const int* __restrict__ src_e, const int* __restrict__ dst_e,
    int* __restrict__ hists,
    const float* __restrict__ X, unsigned short* __restrict__ Xb,
    const float* __restrict__ W1,
    const float* __restrict__ was, const float* __restrict__ wad,
    float* __restrict__ als, float* __restrict__ ald,
    unsigned short* __restrict__ W1p,
    const float* __restrict__ W2, unsigned short* __restrict__ W2p,
    const float* __restrict__ W3, unsigned short* __restrict__ W3p) {
  const int b = blockIdx.x;
  const int tid = threadIdx.x;
  if (b < NBLK1) {                           // ---- coarse histogram (LDS only)
    __shared__ int h[NBKT];
    if (tid < NBKT) h[tid] = 0;
    __syncthreads();
    const int base = b * EPB;
#pragma unroll
    for (int r = 0; r < 4; ++r) {
      int e = base + r * 256 + tid;
      if (e < ETOT) {
        int d = (e < NEDGE) ? dst_e[e] : (e - NEDGE);
        atomicAdd(&h[d >> 8], 1);
      }
    }
    __syncthreads();
    if (tid < NBKT) hists[tid * NBLK1 + b] = h[tid];
  } else if (b < NBLK1 + NB_CVT) {           // ---- cvt X->bf16 + layer-1 logits
    const int g = tid >> 3, gl = tid & 7;    // 32 node-groups x 8 lanes
    const int n = (b - NBLK1) * 32 + g;
    if (n < NNODES) {
      const int k0 = gl * 16;
      const float* xp = X + (size_t)n * 128 + k0;
      float4 xr[4];
      xr[0] = *(const float4*)(xp);
      xr[1] = *(const float4*)(xp + 4);
      xr[2] = *(const float4*)(xp + 8);
      xr[3] = *(const float4*)(xp + 12);
      float xv[16];
#pragma unroll
      for (int q = 0; q < 4; ++q) {
        xv[q * 4 + 0] = xr[q].x; xv[q * 4 + 1] = xr[q].y;
        xv[q * 4 + 2] = xr[q].z; xv[q * 4 + 3] = xr[q].w;
      }
      unsigned short ob[16];
#pragma unroll
      for (int q = 0; q < 16; ++q) ob[q] = f2b(xv[q]);
      *(short8*)(Xb + (size_t)n * 128 + k0) = *(short8*)(&ob[0]);
      *(short8*)(Xb + (size_t)n * 128 + k0 + 8) = *(short8*)(&ob[8]);
      float s[4], d[4];
#pragma unroll
      for (int h = 0; h < 4; ++h) {
        const float* wsp = was + h * 128 + k0;
        const float* wdp = wad + h * 128 + k0;
        float ss = 0.f, dd = 0.f;
#pragma unroll
        for (int q = 0; q < 16; ++q) {
          ss += xv[q] * wsp[q];
          dd += xv[q] * wdp[q];
        }
        s[h] = ss; d[h] = dd;
      }
#pragma unroll
      for (int m = 1; m < 8; m <<= 1)
#pragma unroll
        for (int h = 0; h < 4; ++h) {
          s[h] += __shfl_xor(s[h], m);
          d[h] += __shfl_xor(d[h], m);
        }
      const int hh = gl & 3;
      float sv = (hh == 0) ? s[0] : (hh == 1) ? s[1] : (hh == 2) ? s[2] : s[3];
      float dv = (hh == 0) ? d[0] : (hh == 1) ? d[1] : (hh == 2) ? d[2] : d[3];
      if (gl < 4) als[(size_t)n * 4 + gl] = sv;
      else        ald[(size_t)n * 4 + (gl - 4)] = dv;
    }
  } else if (b < NBLK1 + NB_CVT + 128) {     // ---- pack W1 per head
    int idx = (b - NBLK1 - NB_CVT) * 256 + tid;   // 4*8192
    int h = idx >> 13, r = idx & 8191;
    int j = r & 7, lane = (r >> 3) & 63, t = r >> 9;
    int ks = t & 3, nt = t >> 2;
    int k = ks * 32 + (lane >> 4) * 8 + j;
    int n = nt * 16 + (lane & 15);
    W1p[idx] = f2b(W1[(size_t)k * 256 + h * 64 + n]);
  } else if (b < NBLK1 + NB_CVT + 256) {     // ---- pack W2 (K=256,N=128)
    int idx = (b - NBLK1 - NB_CVT - 128) * 256 + tid;  // 32768
    int j = idx & 7, lane = (idx >> 3) & 63, t = idx >> 9;
    int ks = t % 8, nt = t / 8;
    int k = ks * 32 + (lane >> 4) * 8 + j;
    int n = nt * 16 + (lane & 15);
    W2p[idx] = f2b(W2[(size_t)k * C2 + n]);
  } else {                                    // ---- pack W3 (K=128,N=16,real 10)
    int idx = (b - NBLK1 - NB_CVT - 256) * 256 + tid;  // 2048
    int j = idx & 7, lane = (idx >> 3) & 63, t = idx >> 9;
    int ks = t & 3, nt = t >> 2;
    int k = ks * 32 + (lane >> 4) * 8 + j;
    int n = nt * 16 + (lane & 15);
    W3p[idx] = f2b((n < C3) ? W3[(size_t)k * C3 + n] : 0.f);
  }
}

// ---------------- offset-table scan (exclusive, over SCM ints) ----------------

__global__ __launch_bounds__(256) void k_scanA2(const int* __restrict__ a,
                                                int* __restrict__ bsum) {
  int idx = blockIdx.x * 256 + threadIdx.x;
  int v = (idx < SCM) ? a[idx] : 0;
#pragma unroll
  for (int m = 1; m < 64; m <<= 1) v += __shfl_xor(v, m);
  __shared__ int ws[4];
  int lane = threadIdx.x & 63, wid = threadIdx.x >> 6;
  if (lane == 0) ws[wid] = v;
  __syncthreads();
  if (threadIdx.x == 0) bsum[blockIdx.x] = ws[0] + ws[1] + ws[2] + ws[3];
}

// scanB2 computes its own block-prefix over bsum (scanMid folded in)
__global__ __launch_bounds__(256) void k_scanB2(int* __restrict__ a,
                                                const int* __restrict__ bsum,
                                                int* __restrict__ cb) {
  const int b = blockIdx.x, tid = threadIdx.x;
  const int lane = tid & 63, wid = tid >> 6;
  __shared__ int ws[4];
  __shared__ int ws2[4];
  int part = 0;
  for (int i0 = 0; i0 < SCB; i0 += 256) {
    int i = i0 + tid;
    if (i < b) part += bsum[i];
  }
#pragma unroll
  for (int m = 1; m < 64; m <<= 1) part += __shfl_xor(part, m);
  if (lane == 0) ws2[wid] = part;
  __syncthreads();
  const int boff = ws2[0] + ws2[1] + ws2[2] + ws2[3];
  int idx = b * 256 + tid;
  int v = (idx < SCM) ? a[idx] : 0;
  int s = v;
#pragma unroll
  for (int m = 1; m < 64; m <<= 1) {
    int t = __shfl_up(s, m);
    if (lane >= m) s += t;
  }
  if (lane == 63) ws[wid] = s;
  __syncthreads();
  int woff = 0;
#pragma unroll
  for (int k = 0; k < 4; ++k)
    if (k < wid) woff += ws[k];
  int excl = boff + woff + s - v;
  if (idx < SCM) {
    a[idx] = excl;
    if (idx % NBLK1 == 0) cb[idx / NBLK1] = excl;   // coarse bucket base
  }
  if (b == 0 && tid == 0) cb[NBKT] = ETOT;
}

// ---------------- partition into coarse buckets (LDS atomics only) ----------

__global__ __launch_bounds__(256) void k_part1(const int* __restrict__ src_e,
                                               const int* __restrict__ dst_e,
                                               const int* __restrict__ offs,
                                               unsigned* __restrict__ coarse) {
  __shared__ int cur[NBKT];
  const int b = blockIdx.x;
  const int tid = threadIdx.x;
  if (tid < NBKT) cur[tid] = offs[tid * NBLK1 + b];
  __syncthreads();
  const int base = b * EPB;
#pragma unroll
  for (int r = 0; r < 4; ++r) {
    int e = base + r * 256 + tid;
    if (e < ETOT) {
      int d, s;
      if (e < NEDGE) { d = dst_e[e]; s = src_e[e]; }
      else           { d = e - NEDGE; s = e - NEDGE; }
      int pos = atomicAdd(&cur[d >> 8], 1);
      coarse[pos] = ((unsigned)d << 16) | (unsigned)s;
    }
  }
}

// ---------------- per-bucket fine binning -> rowptr + srcs -------------------

__global__ __launch_bounds__(256) void k_bucket(const unsigned* __restrict__ coarse,
                                                const int* __restrict__ cb,
                                                int* __restrict__ rowptr,
                                                int* __restrict__ srcs) {
  const int b = blockIdx.x;                  // 196 buckets
  const int tid = threadIdx.x;
  const int lane = tid & 63, wid = tid >> 6;
  const int lo = cb[b], hi = cb[b + 1];
  __shared__ int h[256];
  __shared__ int cur[256];
  __shared__ int ws[4];
  h[tid] = 0;
  __syncthreads();
  for (int i = lo + tid; i < hi; i += 256)
    atomicAdd(&h[(coarse[i] >> 16) & 255], 1);
  __syncthreads();
  int v = h[tid];
  int s = v;
#pragma unroll
  for (int m = 1; m < 64; m <<= 1) {
    int t = __shfl_up(s, m);
    if (lane >= m) s += t;
  }
  if (lane == 63) ws[wid] = s;
  __syncthreads();
  int woff = 0;
#pragma unroll
  for (int k = 0; k < 4; ++k)
    if (k < wid) woff += ws[k];
  int ex = woff + s - v;                     // exclusive fine scan
  cur[tid] = lo + ex;
  int d = b * 256 + tid;
  if (d < NNODES) rowptr[d] = lo + ex;
  if (b == NBKT - 1 && tid == 0) rowptr[NNODES] = ETOT;
  __syncthreads();
  for (int i = lo + tid; i < hi; i += 256) {
    unsigned c = coarse[i];
    int pos = atomicAdd(&cur[(c >> 16) & 255], 1);
    srcs[pos] = (int)(c & 0xffffu);
  }
}

// ---------------- layer-1 pre-GEMM aggregation (128 ch, 4 heads) ----

__global__ __launch_bounds__(512) void k_aggP(const int* __restrict__ rowptr,
                                              const int* __restrict__ srcs,
                                              const unsigned short* __restrict__ Xb,
                                              const float* __restrict__ als,
                                              const float* __restrict__ ald,
                                              unsigned short* __restrict__ P) {
  __shared__ float exs[8][16][4];           // [wave][edge][head]
  const int wv = threadIdx.x >> 6;
  const int n = blockIdx.x * 8 + wv;
  const int lane = threadIdx.x & 63;
  const int r0 = rowptr[n], r1 = rowptr[n + 1];
  const int e_lane = lane & 15, hh = lane >> 4;
  const float aldv = ald[(size_t)n * 4 + hh];
  const int ch0 = lane * 2;
  f32x2 ah0 = {0.f, 0.f}, ah1 = {0.f, 0.f}, ah2 = {0.f, 0.f}, ah3 = {0.f, 0.f};
  float den = 0.f;
  for (int i0 = r0; i0 < r1; i0 += 16) {
    const int take = r1 - i0;
    int sidx = srcs[min(i0 + e_lane, r1 - 1)];
    float ev = als[(size_t)sidx * 4 + hh] + aldv;
    ev = (ev > 0.f) ? ev : 0.2f * ev;
    float exv = (e_lane < take) ? __expf(ev) : 0.f;
    den += exv;
    exs[wv][e_lane][hh] = exv;
    unsigned hv[16];
#pragma unroll
    for (int m = 0; m < 16; ++m) {
      int s = __builtin_amdgcn_readlane(sidx, m);
      hv[m] = *(const unsigned*)(Xb + (size_t)s * 128 + ch0);
    }
#pragma unroll
    for (int m = 0; m < 16; ++m) {
      f32x2 e01 = *(const f32x2*)(&exs[wv][m][0]);
      f32x2 e23 = *(const f32x2*)(&exs[wv][m][2]);
      f32x2 x2;
      x2.x = __uint_as_float(hv[m] << 16);
      x2.y = __uint_as_float(hv[m] & 0xffff0000u);
      asm("v_pk_fma_f32 %0, %1, %2, %0 op_sel:[0,0,0] op_sel_hi:[1,0,1]"
          : "+v"(ah0) : "v"(x2), "v"(e01));
      asm("v_pk_fma_f32 %0, %1, %2, %0 op_sel:[0,1,0] op_sel_hi:[1,1,1]"
          : "+v"(ah1) : "v"(x2), "v"(e01));
      asm("v_pk_fma_f32 %0, %1, %2, %0 op_sel:[0,0,0] op_sel_hi:[1,0,1]"
          : "+v"(ah2) : "v"(x2), "v"(e23));
      asm("v_pk_fma_f32 %0, %1, %2, %0 op_sel:[0,1,0] op_sel_hi:[1,1,1]"
          : "+v"(ah3) : "v"(x2), "v"(e23));
    }
  }
#pragma unroll
  for (int m = 1; m < 16; m <<= 1) den += __shfl_xor(den, m);
  float acc[4][2] = {{ah0.x, ah0.y}, {ah1.x, ah1.y}, {ah2.x, ah2.y}, {ah3.x, ah3.y}};
#pragma unroll
  for (int h = 0; h < 4; ++h) {
    float rd = 1.f / (readlane_f(den, h * 16) + 1e-16f);
    ushort2 o; o.x = f2b(acc[h][0] * rd); o.y = f2b(acc[h][1] * rd);
    *(ushort2*)(P + ((size_t)n * 4 + h) * 128 + ch0) = o;
  }
}

// ---------------- FUSED GEMM chain: act1 = lrelu(P@W1+b1); H2 = act1@W2 ------

__global__ __launch_bounds__(256) void k_mmX(
    const unsigned short* __restrict__ P,
    const unsigned short* __restrict__ W1p, const float* __restrict__ b1,
    const unsigned short* __restrict__ W2p,
    const float* __restrict__ as2, const float* __restrict__ ad2,
    unsigned short* __restrict__ Hout,
    float* __restrict__ als, float* __restrict__ ald) {
  __shared__ unsigned short actl[64 * 256];   // 32 KB
  const int wv = threadIdx.x >> 6, lane = threadIdx.x & 63;
  const int row16 = lane & 15;
  const int k0 = (lane >> 4) * 8;
  const int col = lane & 15;
  const int rb = (lane >> 4) * 4;

  // ---- phase A: rows [wv*16, wv*16+16) of act tile
  const int nodebase = blockIdx.x * 64 + wv * 16;
#pragma unroll
  for (int h = 0; h < 4; ++h) {
    const unsigned short* Ph = P + ((size_t)(nodebase + row16) * 4 + h) * 128;
    f32x4 acc[4] = {};
#pragma unroll
    for (int ks = 0; ks < 4; ++ks) {
      short8 a = *(const short8*)(Ph + ks * 32 + k0);
      const short8* bp = (const short8*)(W1p + (size_t)h * 8192) + ks * 64 + lane;
#pragma unroll
      for (int nt = 0; nt < 4; ++nt) {
        short8 b = bp[nt * 256];
        acc[nt] = __builtin_amdgcn_mfma_f32_16x16x32_bf16(a, b, acc[nt], 0, 0, 0);
      }
    }
#pragma unroll
    for (int nt = 0; nt < 4; ++nt) {
      int ch = h * 64 + nt * 16 + col;
      float bb = b1[ch];
#pragma unroll
      for (int j = 0; j < 4; ++j) {
        int row = wv * 16 + rb + j;
        float v = acc[nt][j] + bb;
        v = (v > 0.f) ? v : 0.01f * v;
        unsigned byte = (unsigned)(row * 512 + ch * 2) ^ (unsigned)((row & 7) << 4);
        *(unsigned short*)((char*)actl + byte) = f2b(v);
      }
    }
  }
  __syncthreads();

  // ---- phase B: H2 = act @ W2 (K=256) + layer-2 logits
  const int arow = wv * 16 + row16;
  f32x4 acc2[8] = {};
#pragma unroll
  for (int ks = 0; ks < 8; ++ks) {
    unsigned byte = (unsigned)(arow * 512 + (ks * 32 + k0) * 2) ^
                    (unsigned)((arow & 7) << 4);
    short8 a = *(const short8*)((const char*)actl + byte);
    const short8* bp = (const short8*)W2p + ks * 64 + lane;
#pragma unroll
    for (int nt = 0; nt < 8; ++nt) {
      short8 b = bp[(size_t)nt * 512];
      acc2[nt] = __builtin_amdgcn_mfma_f32_16x16x32_bf16(a, b, acc2[nt], 0, 0, 0);
    }
  }
  const int rbase = blockIdx.x * 64 + wv * 16 + rb;
  float av[8], dv[8];
#pragma unroll
  for (int nt = 0; nt < 8; ++nt) {
    int ch = nt * 16 + col;
    av[nt] = as2[ch];
    dv[nt] = ad2[ch];
#pragma unroll
    for (int j = 0; j < 4; ++j)
      Hout[(size_t)(rbase + j) * C2 + ch] = f2b(acc2[nt][j]);
  }
  float sa[4] = {0.f, 0.f, 0.f, 0.f}, da[4] = {0.f, 0.f, 0.f, 0.f};
#pragma unroll
  for (int nt = 0; nt < 8; ++nt)
#pragma unroll
    for (int j = 0; j < 4; ++j) {
      sa[j] += acc2[nt][j] * av[nt];
      da[j] += acc2[nt][j] * dv[nt];
    }
#pragma unroll
  for (int mask = 1; mask < 16; mask <<= 1)
#pragma unroll
    for (int j = 0; j < 4; ++j) {
      sa[j] += __shfl_xor(sa[j], mask);
      da[j] += __shfl_xor(da[j], mask);
    }
  if (col == 0) {
#pragma unroll
    for (int j = 0; j < 4; ++j) {
      als[rbase + j] = sa[j];
      ald[rbase + j] = da[j];
    }
  }
}

// ---------------- FUSED layer 2 agg + per-wave layer-3 GEMM + att3 logits ----

__global__ __launch_bounds__(512) void k_agg2(const int* __restrict__ rowptr,
                                              const int* __restrict__ srcs,
                                              const unsigned short* __restrict__ Hm,
                                              const float* __restrict__ als,
                                              const float* __restrict__ ald,
                                              const float* __restrict__ bias,
                                              const unsigned short* __restrict__ W3p,
                                              const float* __restrict__ as3,
                                              const float* __restrict__ ad3,
                                              unsigned short* __restrict__ H3b,
                                              float* __restrict__ als3,
                                              float* __restrict__ ald3) {
  __shared__ float exs2[8][16];
  __shared__ unsigned short Xl[8][128];      // 2 KB: activated rows (per-wave slice)
  const int wv = threadIdx.x >> 6;
  const int n = blockIdx.x * 8 + wv;
  const int lane = threadIdx.x & 63;
  const int r0 = rowptr[n], r1 = rowptr[n + 1];
  const int e_lane = lane & 15;
  const int ch0 = lane * 2;
  const float aldm = ald[n];
  f32x2 accP0 = {0.f, 0.f}, accP1 = {0.f, 0.f};
  float den = 0.f;
  for (int i0 = r0; i0 < r1; i0 += 16) {
    const int take = r1 - i0;
    int sidx = srcs[min(i0 + e_lane, r1 - 1)];
    float ev = als[sidx] + aldm;
    ev = (ev > 0.f) ? ev : 0.2f * ev;
    float exv = (lane < 16 && e_lane < take) ? __expf(ev) : 0.f;
    den += exv;
    if (lane < 16) exs2[wv][lane] = exv;
    unsigned hv[16];
#pragma unroll
    for (int m = 0; m < 16; ++m) {
      int s = __builtin_amdgcn_readlane(sidx, m);
      hv[m] = *(const unsigned*)(Hm + (size_t)s * C2 + ch0);
    }
#pragma unroll
    for (int m = 0; m < 16; m += 2) {
      f32x2 ep = *(const f32x2*)(&exs2[wv][m]);
      f32x2 xa, xb;
      xa.x = __uint_as_float(hv[m] << 16);
      xa.y = __uint_as_float(hv[m + 1] << 16);
      xb.x = __uint_as_float(hv[m] & 0xffff0000u);
      xb.y = __uint_as_float(hv[m + 1] & 0xffff0000u);
      asm("v_pk_fma_f32 %0, %1, %2, %0" : "+v"(accP0) : "v"(ep), "v"(xa));
      asm("v_pk_fma_f32 %0, %1, %2, %0" : "+v"(accP1) : "v"(ep), "v"(xb));
    }
  }
#pragma unroll
  for (int mask = 1; mask < 64; mask <<= 1) den += __shfl_xor(den, mask);
  float rden = 1.f / (den + 1e-16f);
  float v0 = (accP0.x + accP0.y) * rden + bias[ch0];
  float v1 = (accP1.x + accP1.y) * rden + bias[ch0 + 1];
  v0 = (v0 > 0.f) ? v0 : 0.01f * v0;
  v1 = (v1 > 0.f) ? v1 : 0.01f * v1;
  ushort2 o; o.x = f2b(v0); o.y = f2b(v1);
  *(ushort2*)(&Xl[wv][ch0]) = o;
  // same-wave LDS write -> read ordering (no block barrier needed)
  asm volatile("s_waitcnt lgkmcnt(0)" ::: "memory");

  // ---- phase 2 (per wave): replicated-A 128->16 GEMM + att3 logits
  const int k0 = (lane >> 4) * 8;
  const int col = lane & 15;
  f32x4 acc2 = {};
#pragma unroll
  for (int ks = 0; ks < 4; ++ks) {
    short8 a = *(const short8*)(&Xl[wv][ks * 32 + k0]);  // broadcast: rows replicated
    short8 b = *((const short8*)W3p + ks * 64 + lane);
    acc2 = __builtin_amdgcn_mfma_f32_16x16x32_bf16(a, b, acc2, 0, 0, 0);
  }
  float hv = acc2[0];                        // all C rows equal; col = lane&15
  const float av = (col < C3) ? as3[col] : 0.f;
  const float dv = (col < C3) ? ad3[col] : 0.f;
  float sa = hv * av, da = hv * dv;
#pragma unroll
  for (int mask = 1; mask < 16; mask <<= 1) {
    sa += __shfl_xor(sa, mask);
    da += __shfl_xor(da, mask);
  }
  if (lane < 16) H3b[(size_t)n * 16 + col] = f2b(hv);
  if (lane == 0) { als3[n] = sa; ald3[n] = da; }
}

// ---------------- layer-3 aggregation + fused pool: 4 nodes/wave -------------

__global__ __launch_bounds__(512) void k_agg3(const int* __restrict__ rowptr,
                                              const int* __restrict__ srcs,
                                              const unsigned short* __restrict__ Hm,
                                              const float* __restrict__ als,
                                              const float* __restrict__ ald,
                                              const float* __restrict__ bias,
                                              float* __restrict__ pooled,
                                              const int* __restrict__ batch) {
  __shared__ int   sid_s[8][4][16];
  __shared__ float exv_s[8][4][16];
  const int wv = threadIdx.x >> 6;
  const int lane = threadIdx.x & 63;
  const int g = lane >> 4, el = lane & 15;
  const int n = blockIdx.x * 32 + wv * 4 + g;
  const bool valid = n < NNODES;
  int r0 = 0, r1 = 0;
  float aldm = 0.f;
  if (valid) { r0 = rowptr[n]; r1 = rowptr[n + 1]; aldm = ald[n]; }
  float acc = 0.f, den = 0.f;
  for (int i0 = r0; i0 < r1; i0 += 16) {
    const int take = r1 - i0;
    int sidx = srcs[min(i0 + el, r1 - 1)];
    float ev = als[sidx] + aldm;
    ev = (ev > 0.f) ? ev : 0.2f * ev;
    float exv = (el < take) ? __expf(ev) : 0.f;
    den += exv;
    sid_s[wv][g][el] = sidx;
    exv_s[wv][g][el] = exv;
#pragma unroll
    for (int m = 0; m < 16; ++m) {
      int s = sid_s[wv][g][m];
      float ex = exv_s[wv][g][m];
      acc += ex * b2f(Hm[(size_t)s * 16 + el]);
    }
  }
#pragma unroll
  for (int mask = 1; mask < 16; mask <<= 1) den += __shfl_xor(den, mask);
  if (valid && el < C3) {
    float val = acc / (den + 1e-16f) + bias[el];
    atomicAdd(&pooled[(size_t)batch[n] * C3 + el], val);
  }
}

// ---------------- log_softmax ----------------

__global__ void k_lsm(const float* __restrict__ pooled, float* __restrict__ dout) {
  int g = blockIdx.x * 256 + threadIdx.x;
  if (g >= NGRAPH) return;
  float v[C3];
  float mx = -1e30f;
#pragma unroll
  for (int c = 0; c < C3; ++c) { v[c] = pooled[g * C3 + c]; mx = fmaxf(mx, v[c]); }
  float ssum = 0.f;
#pragma unroll
  for (int c = 0; c < C3; ++c) ssum += __expf(v[c] - mx);
  float lse = mx + __logf(ssum);
#pragma unroll
  for (int c = 0; c < C3; ++c) {
    dout[g * C3 + c] = v[c] - lse;
    dout[NGRAPH * C3 + g * C3 + c] = v[c];
  }
}

// ---------------- launcher ----------------

extern "C" void kernel_launch(void* const* d_in, const int* in_sizes, int n_in,
                              void* d_out, int out_size, void* d_ws, size_t ws_size,
                              hipStream_t stream) {
  (void)in_sizes; (void)n_in; (void)out_size; (void)ws_size;
  const float* x     = (const float*)d_in[0];
  const int*   eix   = (const int*)d_in[1];
  const int*   batch = (const int*)d_in[3];
  const float* W1 = (const float*)d_in[4];
  const float* as1 = (const float*)d_in[5];
  const float* ad1 = (const float*)d_in[6];
  const float* b1 = (const float*)d_in[7];
  const float* W2 = (const float*)d_in[8];
  const float* as2 = (const float*)d_in[9];
  const float* ad2 = (const float*)d_in[10];
  const float* b2 = (const float*)d_in[11];
  const float* W3 = (const float*)d_in[12];
  const float* as3 = (const float*)d_in[13];
  const float* ad3 = (const float*)d_in[14];
  const float* b3 = (const float*)d_in[15];
  const int* src_e = eix;
  const int* dst_e = eix + NEDGE;

  char* ws = (char*)d_ws;
  size_t off = 0;
  auto carve = [&](size_t bytes) -> char* {
    char* p = ws + off;
    off += (bytes + 511) & ~(size_t)511;
    return p;
  };
  int* hists  = (int*)carve((size_t)SCM * 4);
  int* bsum   = (int*)carve((size_t)SCB * 4);
  int* cb     = (int*)carve((size_t)(NBKT + 1) * 4);
  unsigned* coarse = (unsigned*)carve((size_t)ETOT * 4);
  int* rowptr = (int*)carve((size_t)(NNODES + 1) * 4);
  int* srcs   = (int*)carve((size_t)ETOT * 4);
  float* als  = (float*)carve((size_t)MPAD * H1 * 4);
  float* ald  = (float*)carve((size_t)MPAD * H1 * 4);
  float* als3 = (float*)carve((size_t)MPAD * 4);
  float* ald3 = (float*)carve((size_t)MPAD * 4);
  float* was  = (float*)carve((size_t)512 * 4);
  float* wad  = (float*)carve((size_t)512 * 4);
  unsigned short* Xb  = (unsigned short*)carve((size_t)MPAD * 128 * 2);
  unsigned short* P   = (unsigned short*)carve((size_t)MPAD * 512 * 2);
  unsigned short* Hb  = (unsigned short*)carve((size_t)MPAD * 128 * 2);
  unsigned short* H3b = (unsigned short*)carve((size_t)MPAD * 16 * 2);
  float* pooled = (float*)carve((size_t)NGRAPH * C3 * 4);
  unsigned short* W1p = (unsigned short*)carve((size_t)4 * 8192 * 2);
  unsigned short* W2p = (unsigned short*)carve((size_t)O1 * C2 * 2);
  unsigned short* W3p = (unsigned short*)carve((size_t)C2 * 16 * 2);

  // prep FIRST (k_front's cvt blocks read was/wad); also zeroes pooled
  k_prep<<<1, 512, 0, stream>>>(W1, as1, ad1, was, wad, pooled);
  // fused: coarse histogram + cvt/logits + weight packs
  k_front<<<NBLK1 + NB_CVT + 264, 256, 0, stream>>>(
      src_e, dst_e, hists, x, Xb, W1, was, wad, als, ald, W1p, W2, W2p, W3, W3p);
  // exclusive scan of the (bin, block) offset table; emits coarse bases cb
  k_scanA2<<<SCB, 256, 0, stream>>>(hists, bsum);
  k_scanB2<<<SCB, 256, 0, stream>>>(hists, bsum, cb);
  // partition edges into coarse buckets, then fine-bin -> rowptr + srcs
  k_part1<<<NBLK1, 256, 0, stream>>>(src_e, dst_e, hists, coarse);
  k_bucket<<<NBKT, 256, 0, stream>>>(coarse, cb, rowptr, srcs);

  const int GB = MPAD / 64;        // 782 gemm blocks
  const int NB8 = NNODES / 8;      // 6250 agg blocks
  const int NB32 = (NNODES + 31) / 32;   // 1563 agg3 blocks (4 nodes/wave)

  // layer 1: aggregate X^ in the 128-ch basis (4 heads) -> P (global)
  k_aggP<<<NB8, 512, 0, stream>>>(rowptr, srcs, Xb, als, ald, P);
  // fused GEMM chain: P@W1 -> lrelu -> @W2 -> Hb + layer-2 logits
  k_mmX<<<GB, 256, 0, stream>>>(P, W1p, b1, W2p, as2, ad2, Hb, als, ald);

  // layer 2 agg fused with per-wave layer-3 GEMM + logits (no barrier)
  k_agg2<<<NB8, 512, 0, stream>>>(rowptr, srcs, Hb, als, ald, b2,
                                  W3p, as3, ad3, H3b, als3, ald3);

  // layer 3: aggregate + fused pool
  k_agg3<<<NB32, 512, 0, stream>>>(rowptr, srcs, H3b, als3, ald3, b3, pooled, batch);

  // log_softmax; output = [log_softmax | pooled]
  k_lsm<<<(NGRAPH + 255) / 256, 256, 0, stream>>>(pooled, (float*)d_out);
}